// Round 1
// baseline (18654.886 us; speedup 1.0000x reference)
//
#include <hip/hip_runtime.h>
#include <hip/hip_bf16.h>
#include <cstdint>
#include <cmath>

#define EPSLN 1e-5f

typedef __attribute__((ext_vector_type(8))) short bf16x8;
typedef __attribute__((ext_vector_type(4))) float f32x4;
typedef __attribute__((ext_vector_type(4))) unsigned short u16x4;

constexpr int Bc = 16;
constexpr int Sc = 129;          // T+1
constexpr int Mc = Bc * Sc;      // 2064 rows (real)
constexpr int MP = 2112;         // padded rows = 33*64
constexpr int ITERS = 127;       // T-1

__device__ __forceinline__ void gl2lds16(const void* g, void* l) {
    __builtin_amdgcn_global_load_lds(
        (const __attribute__((address_space(1))) unsigned int*)g,
        (__attribute__((address_space(3))) unsigned int*)l, 16, 0, 0);
}

// ---------------- bf16 MFMA GEMM: C = A @ Bt^T + bias [+res] ----------------
// A: [MP][K] row-major. Bt: [N][K] bf16 (weights pre-transposed).
// EPI: 1 = bias+res -> Cf
//      2 = bias+gelu -> Cb
//      3 = QKV: bias -> Cb always, -> Cf only col<512 (Q needs f32, K/V don't)
//      5 = bias+res -> Cf + per-row LN-stats (sum,sumsq) atomics into stats
// LNA: 0 = A is bf16, staged via global_load_lds
//      1 = A is f32; normalize (x-mean)*rinv using stats, cvt bf16, ds_write (K==512)
template<int EPI, int LNA>
__global__ __launch_bounds__(256)
void mgemm(const void* __restrict__ Av, const __hip_bfloat16* __restrict__ Bt,
           const float* __restrict__ bias, const float* __restrict__ res,
           float* __restrict__ Cf, __hip_bfloat16* __restrict__ Cb,
           float* __restrict__ stats, int M, int N, int K)
{
    __shared__ char lds[16384];      // A tile 8KB @0, B tile 8KB @8192
    const int tid = threadIdx.x;
    const int bm = blockIdx.y << 6, bn = blockIdx.x << 6;
    const int lane = tid & 63, wv = tid >> 6;
    const int wm = (wv & 1) << 5, wn = (wv >> 1) << 5;
    const int fr = lane & 15, kg = lane >> 4;

    int offA[2][2], offB[2][2];
    #pragma unroll
    for (int mi = 0; mi < 2; ++mi)
        #pragma unroll
        for (int kk = 0; kk < 2; ++kk) {
            int kb = (kk << 6) + (kg << 4);
            int ra = wm + (mi << 4) + fr;
            offA[mi][kk] = (ra << 7) + (kb ^ ((ra & 7) << 4));
            int rb = wn + (mi << 4) + fr;
            offB[mi][kk] = 8192 + (rb << 7) + (kb ^ ((rb & 7) << 4));
        }

    // per-thread LN constants (row fixed across K-steps)
    const int arow = tid >> 2, acg = tid & 3;
    float mean = 0.f, rinv = 0.f;
    if (LNA) {
        const int grow = bm + arow;
        float s0 = stats[grow * 2 + 0], s1 = stats[grow * 2 + 1];
        float invn = 1.f / (float)K;
        mean = s0 * invn;
        float var = s1 * invn - mean * mean;
        rinv = rsqrtf(var + EPSLN);
    }

    f32x4 acc[2][2] = {};
    for (int k0 = 0; k0 < K; k0 += 64) {
        if (LNA) {
            // B via global_load_lds
            #pragma unroll
            for (int c = 0; c < 2; ++c) {
                int tid2 = (c << 8) + tid;
                int row = tid2 >> 3;
                int kb  = (tid2 & 7) << 4;
                int swz = kb ^ ((row & 7) << 4);
                const char* sb = (const char*)Bt + (((size_t)(bn + row) * K + k0) << 1) + swz;
                gl2lds16(sb, lds + 8192 + (c << 12) + (wv << 10));
            }
            // A: f32 load + normalize + cvt + swizzled ds_write
            const float* ap = (const float*)Av + (size_t)(bm + arow) * K + k0 + (acg << 4);
            bf16x8 pk[2];
            #pragma unroll
            for (int i = 0; i < 4; ++i) {
                f32x4 x = *(const f32x4*)(ap + (i << 2));
                #pragma unroll
                for (int e = 0; e < 4; ++e) {
                    __hip_bfloat16 bv = __float2bfloat16((x[e] - mean) * rinv);
                    pk[i >> 1][((i & 1) << 2) + e] = *reinterpret_cast<short*>(&bv);
                }
            }
            const int sw = (arow & 7) << 4, bc = acg << 5;
            char* la0 = lds + (arow << 7);
            *(bf16x8*)(la0 + (bc ^ sw)) = pk[0];
            *(bf16x8*)(la0 + ((bc + 16) ^ sw)) = pk[1];
        } else {
            #pragma unroll
            for (int c = 0; c < 2; ++c) {
                int tid2 = (c << 8) + tid;
                int row = tid2 >> 3;
                int kb  = (tid2 & 7) << 4;
                int swz = kb ^ ((row & 7) << 4);
                const char* sa = (const char*)Av + (((size_t)(bm + row) * K + k0) << 1) + swz;
                const char* sb = (const char*)Bt + (((size_t)(bn + row) * K + k0) << 1) + swz;
                char* da = lds + (c << 12) + (wv << 10);
                gl2lds16(sa, da);
                gl2lds16(sb, da + 8192);
            }
        }
        __syncthreads();
        bf16x8 af[2][2], bf_[2][2];
        #pragma unroll
        for (int mi = 0; mi < 2; ++mi)
            #pragma unroll
            for (int kk = 0; kk < 2; ++kk) {
                af[mi][kk]  = *(const bf16x8*)(lds + offA[mi][kk]);
                bf_[mi][kk] = *(const bf16x8*)(lds + offB[mi][kk]);
            }
        #pragma unroll
        for (int kk = 0; kk < 2; ++kk)
            #pragma unroll
            for (int mi = 0; mi < 2; ++mi)
                #pragma unroll
                for (int ni = 0; ni < 2; ++ni)
                    acc[mi][ni] = __builtin_amdgcn_mfma_f32_16x16x32_bf16(
                        af[mi][kk], bf_[ni][kk], acc[mi][ni], 0, 0, 0);
        __syncthreads();
    }

    const int rb4 = kg << 2;
    #pragma unroll
    for (int mi = 0; mi < 2; ++mi)
        #pragma unroll
        for (int r = 0; r < 4; ++r) {
            const int row = bm + wm + (mi << 4) + rb4 + r;
            if (row >= M) continue;                 // uniform over the fr-group
            float vs[2];
            #pragma unroll
            for (int ni = 0; ni < 2; ++ni) {
                const int col = bn + wn + (ni << 4) + fr;
                float v = acc[mi][ni][r] + bias[col];
                if (EPI == 1 || EPI == 5) v += res[(size_t)row * N + col];
                vs[ni] = v;
                if (EPI == 2) {
                    float g = 0.5f * v * (1.f + tanhf(0.7978845608028654f * (v + 0.044715f * v * v * v)));
                    Cb[(size_t)row * N + col] = __float2bfloat16(g);
                } else if (EPI == 3) {
                    if (col < 512) Cf[(size_t)row * N + col] = v;
                    Cb[(size_t)row * N + col] = __float2bfloat16(v);
                } else {
                    Cf[(size_t)row * N + col] = v;
                }
            }
            if (EPI == 5) {
                float sm = vs[0] + vs[1];
                float sq = vs[0] * vs[0] + vs[1] * vs[1];
                #pragma unroll
                for (int m2 = 1; m2 < 16; m2 <<= 1) {
                    sm += __shfl_xor(sm, m2);
                    sq += __shfl_xor(sq, m2);
                }
                if (fr == 0) {
                    atomicAdd(&stats[row * 2 + 0], sm);
                    atomicAdd(&stats[row * 2 + 1], sq);
                }
            }
        }
}

// ---------------- fused halting GEMM + ACT bookkeeping + LN + blend ----------------
// z = tanh(curr@Wh1+bh1)@Wh2 via split-bf16 (Ah*Bh + Ah*Bl + Al*Bh), A split from
// curr f32 on the fly. Per row-block (gridDim.x==8 column blocks), the LAST block
// to finish (tail-elect via counter) performs the haltblend for its 64 rows.
__global__ __launch_bounds__(256)
void halt_fused(const float* __restrict__ curr,
                const __hip_bfloat16* __restrict__ Bhp, const __hip_bfloat16* __restrict__ Blp,
                const float* __restrict__ bh1, const float* __restrict__ Wh2,
                float* __restrict__ zbuf, unsigned int* __restrict__ cnt,
                const float* __restrict__ lnsw, const float* __restrict__ lnso,
                float* __restrict__ lanh, float* __restrict__ lah,
                float* __restrict__ h, __hip_bfloat16* __restrict__ hb,
                float* __restrict__ hout, float* __restrict__ stats, int M)
{
    __shared__ char lds[32768];      // Ah@0 Al@8192 Bh@16384 Bl@24576
    __shared__ int tailflag;
    const int tid = threadIdx.x;
    const int bm = blockIdx.y << 6, bn = blockIdx.x << 6;
    const int lane = tid & 63, wv = tid >> 6;
    const int wm = (wv & 1) << 5, wn = (wv >> 1) << 5;
    const int fr = lane & 15, kg = lane >> 4;
    const int arow = tid >> 2, acg = tid & 3;

    int offA[2][2], offB[2][2];
    #pragma unroll
    for (int mi = 0; mi < 2; ++mi)
        #pragma unroll
        for (int kk = 0; kk < 2; ++kk) {
            int kb = (kk << 6) + (kg << 4);
            int ra = wm + (mi << 4) + fr;
            offA[mi][kk] = (ra << 7) + (kb ^ ((ra & 7) << 4));
            int rb = wn + (mi << 4) + fr;
            offB[mi][kk] = 16384 + (rb << 7) + (kb ^ ((rb & 7) << 4));
        }

    f32x4 acc[2][2] = {};
    for (int k0 = 0; k0 < 512; k0 += 64) {
        // B hi/lo via global_load_lds
        #pragma unroll
        for (int c = 0; c < 2; ++c) {
            int tid2 = (c << 8) + tid;
            int row = tid2 >> 3;
            int kb  = (tid2 & 7) << 4;
            int swz = kb ^ ((row & 7) << 4);
            size_t boff = (((size_t)(bn + row) * 512 + k0) << 1) + swz;
            char* db = lds + 16384 + (c << 12) + (wv << 10);
            gl2lds16((const char*)Bhp + boff, db);
            gl2lds16((const char*)Blp + boff, db + 8192);
        }
        // A: load curr f32, split hi/lo bf16, swizzled ds_write
        const float* ap = curr + (size_t)(bm + arow) * 512 + k0 + (acg << 4);
        bf16x8 phh[2], pll[2];
        #pragma unroll
        for (int i = 0; i < 4; ++i) {
            f32x4 x = *(const f32x4*)(ap + (i << 2));
            #pragma unroll
            for (int e = 0; e < 4; ++e) {
                __hip_bfloat16 hv = __float2bfloat16(x[e]);
                float lo = x[e] - __bfloat162float(hv);
                __hip_bfloat16 lv = __float2bfloat16(lo);
                phh[i >> 1][((i & 1) << 2) + e] = *reinterpret_cast<short*>(&hv);
                pll[i >> 1][((i & 1) << 2) + e] = *reinterpret_cast<short*>(&lv);
            }
        }
        {
            const int sw = (arow & 7) << 4, bc = acg << 5;
            char* la0 = lds + (arow << 7);
            *(bf16x8*)(la0 + (bc ^ sw)) = phh[0];
            *(bf16x8*)(la0 + ((bc + 16) ^ sw)) = phh[1];
            *(bf16x8*)(la0 + 8192 + (bc ^ sw)) = pll[0];
            *(bf16x8*)(la0 + 8192 + ((bc + 16) ^ sw)) = pll[1];
        }
        __syncthreads();
        bf16x8 ah[2][2], al[2][2], bh_[2][2], bl_[2][2];
        #pragma unroll
        for (int mi = 0; mi < 2; ++mi)
            #pragma unroll
            for (int kk = 0; kk < 2; ++kk) {
                ah[mi][kk]  = *(const bf16x8*)(lds + offA[mi][kk]);
                al[mi][kk]  = *(const bf16x8*)(lds + offA[mi][kk] + 8192);
                bh_[mi][kk] = *(const bf16x8*)(lds + offB[mi][kk]);
                bl_[mi][kk] = *(const bf16x8*)(lds + offB[mi][kk] + 8192);
            }
        #pragma unroll
        for (int kk = 0; kk < 2; ++kk)
            #pragma unroll
            for (int mi = 0; mi < 2; ++mi)
                #pragma unroll
                for (int ni = 0; ni < 2; ++ni) {
                    acc[mi][ni] = __builtin_amdgcn_mfma_f32_16x16x32_bf16(
                        ah[mi][kk], bh_[ni][kk], acc[mi][ni], 0, 0, 0);
                    acc[mi][ni] = __builtin_amdgcn_mfma_f32_16x16x32_bf16(
                        ah[mi][kk], bl_[ni][kk], acc[mi][ni], 0, 0, 0);
                    acc[mi][ni] = __builtin_amdgcn_mfma_f32_16x16x32_bf16(
                        al[mi][kk], bh_[ni][kk], acc[mi][ni], 0, 0, 0);
                }
        __syncthreads();
    }

    // z epilogue -> zbuf atomics
    float b_[2], w0_[2], w1_[2];
    #pragma unroll
    for (int ni = 0; ni < 2; ++ni) {
        int col = bn + wn + (ni << 4) + fr;
        b_[ni] = bh1[col];
        w0_[ni] = Wh2[col * 2 + 0];
        w1_[ni] = Wh2[col * 2 + 1];
    }
    #pragma unroll
    for (int mi = 0; mi < 2; ++mi)
        #pragma unroll
        for (int r = 0; r < 4; ++r) {
            float v0 = tanhf(acc[mi][0][r] + b_[0]);
            float v1 = tanhf(acc[mi][1][r] + b_[1]);
            float p0 = v0 * w0_[0] + v1 * w0_[1];
            float p1 = v0 * w1_[0] + v1 * w1_[1];
            #pragma unroll
            for (int m2 = 1; m2 < 16; m2 <<= 1) {
                p0 += __shfl_xor(p0, m2);
                p1 += __shfl_xor(p1, m2);
            }
            if (fr == 0) {
                int row = bm + wm + (mi << 4) + (kg << 2) + r;
                if (row < M) {
                    atomicAdd(&zbuf[row * 2 + 0], p0);
                    atomicAdd(&zbuf[row * 2 + 1], p1);
                }
            }
        }

    // tail election: last of the 8 column-blocks for this bm does the blend
    __threadfence();
    __syncthreads();
    if (tid == 0) {
        unsigned int old = atomicAdd(&cnt[blockIdx.y], 1u);
        tailflag = (old == 7u) ? 1 : 0;
        if (old == 7u)
            __hip_atomic_store(&cnt[blockIdx.y], 0u, __ATOMIC_RELAXED, __HIP_MEMORY_SCOPE_AGENT);
    }
    __syncthreads();
    if (!tailflag) return;
    __threadfence();

    const int row = bm + arow;
    if (row >= M) return;            // uniform per 4-lane group

    float z0 = __hip_atomic_load(&zbuf[row * 2 + 0], __ATOMIC_RELAXED, __HIP_MEMORY_SCOPE_AGENT) + 2.f;
    float z1 = __hip_atomic_load(&zbuf[row * 2 + 1], __ATOMIC_RELAXED, __HIP_MEMORY_SCOPE_AGENT) - 2.f;
    float mxz = fmaxf(z0, z1);
    float lse = mxz + logf(expf(z0 - mxz) + expf(z1 - mxz));
    float lg0 = z0 - lse, lg1 = z1 - lse;
    float ln_ = lanh[row], la_ = lah[row];
    float lhalt = ln_ + lg1;
    float hl = expf(la_);            // PRE-update lah
    float ph = expf(lhalt);

    const float* cp = curr + (size_t)row * 512;
    float sm = 0.f, sq = 0.f;
    #pragma unroll 8
    for (int j = 0; j < 32; ++j) {
        f32x4 x = *(const f32x4*)(cp + (acg << 2) + (j << 4));
        sm += x[0] + x[1] + x[2] + x[3];
        sq += x[0] * x[0] + x[1] * x[1] + x[2] * x[2] + x[3] * x[3];
    }
    sm += __shfl_xor(sm, 1); sm += __shfl_xor(sm, 2);
    sq += __shfl_xor(sq, 1); sq += __shfl_xor(sq, 2);
    float mean = sm * (1.f / 512.f);
    float inv = rsqrtf(sq * (1.f / 512.f) - mean * mean + EPSLN);

    if (acg == 0) {
        lanh[row] = ln_ + lg0;
        float m3 = fmaxf(la_, lhalt);
        lah[row] = m3 + logf(expf(la_ - m3) + expf(lhalt - m3));
        __hip_atomic_store(&zbuf[row * 2 + 0], 0.f, __ATOMIC_RELAXED, __HIP_MEMORY_SCOPE_AGENT);
        __hip_atomic_store(&zbuf[row * 2 + 1], 0.f, __ATOMIC_RELAXED, __HIP_MEMORY_SCOPE_AGENT);
        stats[row * 2 + 0] = 0.f;    // reset LN stats for next iteration
        stats[row * 2 + 1] = 0.f;
    }

    #pragma unroll 4
    for (int j = 0; j < 32; ++j) {
        const int c = (acg << 2) + (j << 4);
        const size_t idx = (size_t)row * 512 + c;
        f32x4 x  = *(const f32x4*)(cp + c);
        f32x4 sv = *(const f32x4*)(lnsw + c);
        f32x4 ov = *(const f32x4*)(lnso + c);
        f32x4 hv  = *(f32x4*)(h + idx);
        f32x4 hov = *(f32x4*)(hout + idx);
        u16x4 hbv;
        #pragma unroll
        for (int e = 0; e < 4; ++e) {
            float cl = (x[e] - mean) * inv * sv[e] + ov[e];
            float hn = hl * hv[e] + (1.f - hl) * cl;
            hv[e] = hn;
            __hip_bfloat16 bb = __float2bfloat16(hn);
            hbv[e] = *reinterpret_cast<unsigned short*>(&bb);
            hov[e] += ph * cl;
        }
        *(f32x4*)(h + idx) = hv;
        *(u16x4*)(reinterpret_cast<unsigned short*>(hb) + idx) = hbv;
        *(f32x4*)(hout + idx) = hov;
    }
}

// ---------------- MFMA attention ----------------
// grid (5 q-chunks, 8 heads, 16 batch), 256 threads.
#define KT_BASE 0          // [144][128B] XOR-swizzled K (B-layout)   18432
#define VT_BASE 18432      // [64][168] bf16 V^T (stride 336B)        21504
#define QC_BASE 39936      // [32][72] bf16 q+cb (stride 144B)         4608
#define S_BASE  44544      // [32][148] f32 logits                    18944
#define P_BASE  63488      // [32][168] bf16 softmax (stride 336B)    10752
#define R_BASE  74240      // [32][8] f32 rel logits                   1024
__global__ __launch_bounds__(256)
void attn_mfma(const float* __restrict__ qkv, const __hip_bfloat16* __restrict__ qkvb,
               const float* __restrict__ rk7, const float* __restrict__ cbias,
               const float* __restrict__ rbias, __hip_bfloat16* __restrict__ aout)
{
    __shared__ char lds[75264];
    const int tid = threadIdx.x;
    const int chunk = blockIdx.x, hh = blockIdx.y, b = blockIdx.z;
    const int q0 = chunk << 5;
    const int lane = tid & 63, wv = tid >> 6;
    const int fr = lane & 15, kg = lane >> 4;
    const size_t qrow0 = (size_t)b * Sc;
    const short* qs = (const short*)qkvb;

    // zero Kt pad rows 129..143
    if (tid < 120) {
        f32x4 zz = {};
        *(f32x4*)(lds + KT_BASE + 129 * 128 + tid * 16) = zz;
    }
    // stage Kt (rows 0..128) via global_load_lds, XOR pre-swizzled source
    #pragma unroll
    for (int i = 0; i < 5; ++i) {
        int idx = i * 256 + tid;
        if (idx < 1152) {
            int row = idx >> 3, ch = idx & 7;
            if (row <= 128) {
                const char* src = (const char*)qkvb +
                    (((qrow0 + row) * 1536 + 512 + (size_t)hh * 64) << 1) + ((ch ^ (row & 7)) << 4);
                gl2lds16(src, lds + KT_BASE + idx * 16);
            }
        }
    }
    // stage V^T: Vt[d][T], zero-padded T>=129
    #pragma unroll
    for (int i = 0; i < 6; ++i) {
        int idx = i * 256 + tid;
        if (idx < 1344) {
            int d = idx / 21, g = idx % 21;
            int T0 = g * 8;
            bf16x8 pk;
            #pragma unroll
            for (int j = 0; j < 8; ++j) {
                int T = T0 + j;
                pk[j] = (T <= 128) ? qs[(qrow0 + T) * 1536 + 1024 + hh * 64 + d] : (short)0;
            }
            *(bf16x8*)(lds + VT_BASE + d * 336 + T0 * 2) = pk;
        }
    }
    // stage Qc = bf16(q + content_bias)
    #pragma unroll
    for (int i = 0; i < 8; ++i) {
        int idx = i * 256 + tid;
        int row = idx >> 6, d = idx & 63;
        float v = qkv[(qrow0 + q0 + row) * 1536 + hh * 64 + d] + cbias[hh * 64 + d];
        *(__hip_bfloat16*)(lds + QC_BASE + row * 144 + d * 2) = __float2bfloat16(v);
    }
    // R[row][c] = (q + rbias) . rk7[c]
    if (tid < 224) {
        int row = tid / 7, c = tid % 7;
        const float* qp  = qkv + (qrow0 + q0 + row) * 1536 + hh * 64;
        const float* rp  = rk7 + c * 512 + hh * 64;
        const float* rbp = rbias + hh * 64;
        float a = 0.f;
        #pragma unroll 8
        for (int d = 0; d < 64; ++d) a += (qp[d] + rbp[d]) * rp[d];
        *(float*)(lds + R_BASE + (row * 8 + c) * 4) = a;
    }
    __syncthreads();

    // QK^T: 9 N-tiles over 4 waves
    f32x4 acc[2][3] = {};
    #pragma unroll
    for (int ni = 0; ni < 3; ++ni) {
        int nt = wv + ni * 4;
        if (nt > 8) continue;
        #pragma unroll
        for (int mt = 0; mt < 2; ++mt)
            #pragma unroll
            for (int ks = 0; ks < 2; ++ks) {
                bf16x8 a = *(const bf16x8*)(lds + QC_BASE + (mt * 16 + fr) * 144 + ks * 64 + kg * 16);
                int rowb = nt * 16 + fr;
                bf16x8 bb = *(const bf16x8*)(lds + KT_BASE + rowb * 128 +
                                             ((ks * 64 + kg * 16) ^ ((rowb & 7) << 4)));
                acc[mt][ni] = __builtin_amdgcn_mfma_f32_16x16x32_bf16(a, bb, acc[mt][ni], 0, 0, 0);
            }
    }
    // S = (cl + rl)*scale, masked
    #pragma unroll
    for (int ni = 0; ni < 3; ++ni) {
        int nt = wv + ni * 4;
        if (nt > 8) continue;
        int col = nt * 16 + fr;
        #pragma unroll
        for (int mt = 0; mt < 2; ++mt)
            #pragma unroll
            for (int r = 0; r < 4; ++r) {
                int row = mt * 16 + kg * 4 + r;
                float sv;
                if (col > 128) sv = -1e30f;
                else {
                    int delta = q0 + row - col;
                    int c = delta >= 3 ? 3 : (delta <= -3 ? 4 : (delta < 0 ? delta + 7 : delta));
                    float rl = *(const float*)(lds + R_BASE + (row * 8 + c) * 4);
                    sv = (acc[mt][ni][r] + rl) * 0.125f;
                }
                *(float*)(lds + S_BASE + (row * 148 + col) * 4) = sv;
            }
    }
    __syncthreads();

    // softmax (8 rows per wave) -> P bf16
    #pragma unroll
    for (int rr = 0; rr < 8; ++rr) {
        int row = wv * 8 + rr;
        const float* srow = (const float*)(lds + S_BASE + row * 148 * 4);
        float s0 = srow[lane];
        float s1 = srow[lane + 64];
        float s2 = (lane < 16) ? srow[lane + 128] : -1e30f;
        float mx = fmaxf(fmaxf(s0, s1), s2);
        #pragma unroll
        for (int m2 = 1; m2 < 64; m2 <<= 1) mx = fmaxf(mx, __shfl_xor(mx, m2));
        float e0 = expf(s0 - mx), e1 = expf(s1 - mx);
        float e2 = (lane < 16) ? expf(s2 - mx) : 0.f;
        float sum = e0 + e1 + e2;
        #pragma unroll
        for (int m2 = 1; m2 < 64; m2 <<= 1) sum += __shfl_xor(sum, m2);
        float inv = 1.f / sum;
        __hip_bfloat16* prow = (__hip_bfloat16*)(lds + P_BASE + row * 336);
        prow[lane] = __float2bfloat16(e0 * inv);
        prow[lane + 64] = __float2bfloat16(e1 * inv);
        if (lane < 32) prow[lane + 128] = __float2bfloat16((lane < 16) ? e2 * inv : 0.f);
    }
    __syncthreads();

    // PV: wave owns 16 output dims
    f32x4 acc2[2] = {};
    #pragma unroll
    for (int mt = 0; mt < 2; ++mt)
        #pragma unroll
        for (int ks = 0; ks < 5; ++ks) {
            bf16x8 a  = *(const bf16x8*)(lds + P_BASE + (mt * 16 + fr) * 336 + ks * 64 + kg * 16);
            bf16x8 bb = *(const bf16x8*)(lds + VT_BASE + (wv * 16 + fr) * 336 + ks * 64 + kg * 16);
            acc2[mt] = __builtin_amdgcn_mfma_f32_16x16x32_bf16(a, bb, acc2[mt], 0, 0, 0);
        }
    #pragma unroll
    for (int mt = 0; mt < 2; ++mt)
        #pragma unroll
        for (int r = 0; r < 4; ++r) {
            int t = q0 + mt * 16 + kg * 4 + r;
            if (t <= 128)
                aout[(qrow0 + t) * 512 + hh * 64 + wv * 16 + fr] = __float2bfloat16(acc2[mt][r]);
        }
}

// ---------------- setup kernels ----------------
__global__ __launch_bounds__(256)
void emb_kernel(const float* __restrict__ x, const float* __restrict__ We,
                const float* __restrict__ eos, const float* __restrict__ s,
                const float* __restrict__ o, float* __restrict__ h,
                __hip_bfloat16* __restrict__ hb)
{
    int row = blockIdx.x, tid = threadIdx.x;
    int b = row / Sc, t = row % Sc;
    __shared__ float xs[64];
    if (t != 128 && tid < 64) xs[tid] = x[((size_t)b * 128 + t) * 64 + tid];
    __syncthreads();
    float v0, v1;
    if (t == 128) {
        v0 = eos[tid]; v1 = eos[tid + 256];
    } else {
        v0 = 0.f; v1 = 0.f;
        #pragma unroll 8
        for (int k = 0; k < 64; ++k) {
            float xv = xs[k];
            v0 = fmaf(xv, We[k * 512 + tid], v0);
            v1 = fmaf(xv, We[k * 512 + tid + 256], v1);
        }
    }
    float sum = v0 + v1, sq = v0 * v0 + v1 * v1;
    #pragma unroll
    for (int m2 = 1; m2 < 64; m2 <<= 1) { sum += __shfl_xor(sum, m2); sq += __shfl_xor(sq, m2); }
    __shared__ float ssum[4], ssq[4];
    if ((tid & 63) == 0) { ssum[tid >> 6] = sum; ssq[tid >> 6] = sq; }
    __syncthreads();
    float tot = ssum[0] + ssum[1] + ssum[2] + ssum[3];
    float totq = ssq[0] + ssq[1] + ssq[2] + ssq[3];
    float mean = tot * (1.f / 512.f);
    float inv = rsqrtf(totq * (1.f / 512.f) - mean * mean + EPSLN);
    float h0 = (v0 - mean) * inv * s[tid] + o[tid];
    float h1 = (v1 - mean) * inv * s[tid + 256] + o[tid + 256];
    h[(size_t)row * 512 + tid] = h0;
    h[(size_t)row * 512 + tid + 256] = h1;
    hb[(size_t)row * 512 + tid] = __float2bfloat16(h0);
    hb[(size_t)row * 512 + tid + 256] = __float2bfloat16(h1);
}

__global__ __launch_bounds__(256)
void rk7_kernel(const float* __restrict__ pos, const float* __restrict__ Wk,
                const float* __restrict__ bk, float* __restrict__ rk7)
{
    int c = blockIdx.x, tid = threadIdx.x;
    __shared__ float ps[512];
    ps[tid] = pos[c * 512 + tid];
    ps[tid + 256] = pos[c * 512 + tid + 256];
    __syncthreads();
    float a0 = bk[tid], a1 = bk[tid + 256];
    for (int k = 0; k < 512; ++k) {
        float pv = ps[k];
        a0 = fmaf(pv, Wk[(size_t)k * 512 + tid], a0);
        a1 = fmaf(pv, Wk[(size_t)k * 512 + tid + 256], a1);
    }
    rk7[c * 512 + tid] = a0;
    rk7[c * 512 + tid + 256] = a1;
}

__global__ __launch_bounds__(256)
void pack_qkvT(const float* __restrict__ Wq, const float* __restrict__ Wk,
               const float* __restrict__ Wv, __hip_bfloat16* __restrict__ Wt)
{
    int idx = blockIdx.x * 256 + threadIdx.x;
    if (idx >= 1536 * 512) return;
    int n = idx >> 9, k = idx & 511;
    const float* src = (n < 512) ? Wq : (n < 1024) ? Wk : Wv;
    int nc = n & 511;
    Wt[idx] = __float2bfloat16(src[(size_t)k * 512 + nc]);
}

__global__ __launch_bounds__(256)
void transposeT(const float* __restrict__ W, __hip_bfloat16* __restrict__ Wt, int K, int N)
{
    int idx = blockIdx.x * 256 + threadIdx.x;
    if (idx >= K * N) return;
    int n = idx / K, k = idx - n * K;
    Wt[idx] = __float2bfloat16(W[(size_t)k * N + n]);
}

// Wt[n][k] = bf16(W[k][n] * s[k])   (fold LN scale into W1)
__global__ __launch_bounds__(256)
void transposeT_scale(const float* __restrict__ W, const float* __restrict__ s,
                      __hip_bfloat16* __restrict__ Wt, int K, int N)
{
    int idx = blockIdx.x * 256 + threadIdx.x;
    if (idx >= K * N) return;
    int n = idx / K, k = idx - n * K;
    Wt[idx] = __float2bfloat16(W[(size_t)k * N + n] * s[k]);
}

// bf[n] = b[n] + sum_k o[k]*W[k][n]   (fold LN offset into b1)
__global__ __launch_bounds__(256)
void fold_b1(const float* __restrict__ W, const float* __restrict__ o,
             const float* __restrict__ b, float* __restrict__ bf, int K, int N)
{
    int n = blockIdx.x * 256 + threadIdx.x;
    if (n >= N) return;
    float a = b[n];
    for (int k = 0; k < K; ++k) a += o[k] * W[(size_t)k * N + n];
    bf[n] = a;
}

__global__ __launch_bounds__(256)
void transposeT_split(const float* __restrict__ W, __hip_bfloat16* __restrict__ Whi,
                      __hip_bfloat16* __restrict__ Wlo, int K, int N)
{
    int idx = blockIdx.x * 256 + threadIdx.x;
    if (idx >= K * N) return;
    int n = idx / K, k = idx - n * K;
    float v = W[(size_t)k * N + n];
    __hip_bfloat16 hi = __float2bfloat16(v);
    Whi[idx] = hi;
    Wlo[idx] = __float2bfloat16(v - __bfloat162float(hi));
}

__global__ __launch_bounds__(256)
void pack_bias(const float* __restrict__ bq, const float* __restrict__ bk,
               const float* __restrict__ bv, float* __restrict__ bqkv)
{
    int idx = blockIdx.x * 256 + threadIdx.x;
    if (idx < 1536)
        bqkv[idx] = (idx < 512) ? bq[idx] : (idx < 1024) ? bk[idx - 512] : bv[idx - 1024];
}

__global__ __launch_bounds__(256)
void init_kernel(float* __restrict__ lanh, float* __restrict__ lah,
                 float* __restrict__ zbuf, float* __restrict__ stats,
                 unsigned int* __restrict__ cnt)
{
    int idx = blockIdx.x * 256 + threadIdx.x;
    if (idx < Mc) {
        lanh[idx] = 0.f; lah[idx] = -64.f;
        zbuf[idx * 2 + 0] = 0.f; zbuf[idx * 2 + 1] = 0.f;
    }
    if (idx < MP) {
        stats[idx * 2 + 0] = 0.f; stats[idx * 2 + 1] = 0.f;
    }
    if (idx < 64) cnt[idx] = 0u;
}

// ---------------- host launcher ----------------
extern "C" void kernel_launch(void* const* d_in, const int* in_sizes, int n_in,
                              void* d_out, int out_size, void* d_ws, size_t ws_size,
                              hipStream_t stream)
{
    const float* x     = (const float*)d_in[0];
    const float* We    = (const float*)d_in[1];
    const float* eos   = (const float*)d_in[2];
    const float* Wq    = (const float*)d_in[3];
    const float* bq    = (const float*)d_in[4];
    const float* Wk    = (const float*)d_in[5];
    const float* bk    = (const float*)d_in[6];
    const float* Wv    = (const float*)d_in[7];
    const float* bv    = (const float*)d_in[8];
    const float* Wo    = (const float*)d_in[9];
    const float* bo    = (const float*)d_in[10];
    const float* cbias = (const float*)d_in[11];
    const float* rbias = (const float*)d_in[12];
    const float* pos   = (const float*)d_in[13];
    const float* ln2s  = (const float*)d_in[14];
    const float* ln2o  = (const float*)d_in[15];
    const float* lnos  = (const float*)d_in[16];
    const float* lnoo  = (const float*)d_in[17];
    const float* W1    = (const float*)d_in[18];
    const float* b1    = (const float*)d_in[19];
    const float* W2    = (const float*)d_in[20];
    const float* b2    = (const float*)d_in[21];
    const float* Wh1   = (const float*)d_in[22];
    const float* bh1   = (const float*)d_in[23];
    const float* Wh2   = (const float*)d_in[24];
    (void)in_sizes; (void)n_in; (void)ws_size;

    char* wp = (char*)d_ws;
    auto alloc = [&](size_t bytes) { char* p = wp; wp += (bytes + 255) & ~(size_t)255; return p; };
    float*          h     = (float*)alloc((size_t)MP * 512 * 4);
    __hip_bfloat16* hb    = (__hip_bfloat16*)alloc((size_t)MP * 512 * 2);
    float*          qkv   = (float*)alloc((size_t)MP * 1536 * 4);
    __hip_bfloat16* qkvb  = (__hip_bfloat16*)alloc((size_t)MP * 1536 * 2);
    __hip_bfloat16* abufb = (__hip_bfloat16*)alloc((size_t)MP * 512 * 2);
    float*          hmid  = (float*)alloc((size_t)MP * 512 * 4);
    __hip_bfloat16* g1b   = (__hip_bfloat16*)alloc((size_t)MP * 1024 * 2);
    float*          curr  = (float*)alloc((size_t)MP * 512 * 4);
    __hip_bfloat16* WqkvT = (__hip_bfloat16*)alloc((size_t)1536 * 512 * 2);
    __hip_bfloat16* WoT   = (__hip_bfloat16*)alloc((size_t)512 * 512 * 2);
    __hip_bfloat16* W1T   = (__hip_bfloat16*)alloc((size_t)1024 * 512 * 2);
    __hip_bfloat16* W2T   = (__hip_bfloat16*)alloc((size_t)512 * 1024 * 2);
    __hip_bfloat16* Wh1Th = (__hip_bfloat16*)alloc((size_t)512 * 512 * 2);
    __hip_bfloat16* Wh1Tl = (__hip_bfloat16*)alloc((size_t)512 * 512 * 2);
    float*          bqkv  = (float*)alloc(1536 * 4);
    float*          b1f   = (float*)alloc(1024 * 4);
    float*          rk7   = (float*)alloc(7 * 512 * 4);
    float*          lanh  = (float*)alloc(Mc * 4);
    float*          lah   = (float*)alloc(Mc * 4);
    float*          zbuf  = (float*)alloc((size_t)Mc * 2 * 4);
    float*          stats = (float*)alloc((size_t)MP * 2 * 4);
    unsigned int*   cnt   = (unsigned int*)alloc(64 * 4);
    float* hout = (float*)d_out;

    hipMemsetAsync(d_out, 0, (size_t)out_size * sizeof(float), stream);
    init_kernel<<<(MP + 255) / 256, 256, 0, stream>>>(lanh, lah, zbuf, stats, cnt);
    pack_qkvT<<<(1536 * 512 + 255) / 256, 256, 0, stream>>>(Wq, Wk, Wv, WqkvT);
    transposeT<<<(512 * 512 + 255) / 256, 256, 0, stream>>>(Wo, WoT, 512, 512);
    transposeT_scale<<<(512 * 1024 + 255) / 256, 256, 0, stream>>>(W1, ln2s, W1T, 512, 1024);
    fold_b1<<<4, 256, 0, stream>>>(W1, ln2o, b1, b1f, 512, 1024);
    transposeT<<<(1024 * 512 + 255) / 256, 256, 0, stream>>>(W2, W2T, 1024, 512);
    transposeT_split<<<(512 * 512 + 255) / 256, 256, 0, stream>>>(Wh1, Wh1Th, Wh1Tl, 512, 512);
    pack_bias<<<(1536 + 255) / 256, 256, 0, stream>>>(bq, bk, bv, bqkv);
    rk7_kernel<<<7, 256, 0, stream>>>(pos, Wk, bk, rk7);
    emb_kernel<<<Mc, 256, 0, stream>>>(x, We, eos, lnos, lnoo, h, hb);

    dim3 gQKV(1536 / 64, 33), g512(512 / 64, 33), g1024(1024 / 64, 33);
    for (int it = 0; it < ITERS; ++it) {
        mgemm<3, 0><<<gQKV, 256, 0, stream>>>(hb, WqkvT, bqkv, nullptr, qkv, qkvb, nullptr, Mc, 1536, 512);
        attn_mfma<<<dim3(5, 8, 16), 256, 0, stream>>>(qkv, qkvb, rk7, cbias, rbias, abufb);
        mgemm<5, 0><<<g512, 256, 0, stream>>>(abufb, WoT, bo, h, hmid, nullptr, stats, Mc, 512, 512);
        mgemm<2, 1><<<g1024, 256, 0, stream>>>(hmid, W1T, b1f, nullptr, nullptr, g1b, stats, Mc, 1024, 512);
        mgemm<1, 0><<<g512, 256, 0, stream>>>(g1b, W2T, b2, hmid, curr, nullptr, nullptr, Mc, 512, 1024);
        halt_fused<<<g512, 256, 0, stream>>>(curr, Wh1Th, Wh1Tl, bh1, Wh2, zbuf, cnt,
                                             lnos, lnoo, lanh, lah, h, hb, hout, stats, Mc);
    }
}

// Round 2
// 13610.869 us; speedup vs baseline: 1.3706x; 1.3706x over previous
//
#include <hip/hip_runtime.h>
#include <hip/hip_bf16.h>
#include <cstdint>
#include <cmath>

#define EPSLN 1e-5f

typedef __attribute__((ext_vector_type(8))) short bf16x8;
typedef __attribute__((ext_vector_type(4))) float f32x4;

constexpr int Bc = 16;
constexpr int Sc = 129;          // T+1
constexpr int Mc = Bc * Sc;      // 2064 rows (real)
constexpr int MP = 2112;         // padded rows = 33*64 = 66*32
constexpr int ITERS = 127;       // T-1

__device__ __forceinline__ void gl2lds16(const void* g, void* l) {
    __builtin_amdgcn_global_load_lds(
        (const __attribute__((address_space(1))) unsigned int*)g,
        (__attribute__((address_space(3))) unsigned int*)l, 16, 0, 0);
}

template<int N> __device__ __forceinline__ void vmw() {
    if constexpr (N == 0) asm volatile("s_waitcnt vmcnt(0)" ::: "memory");
    else if constexpr (N == 3) asm volatile("s_waitcnt vmcnt(3)" ::: "memory");
    else if constexpr (N == 4) asm volatile("s_waitcnt vmcnt(4)" ::: "memory");
    else if constexpr (N == 6) asm volatile("s_waitcnt vmcnt(6)" ::: "memory");
    else if constexpr (N == 8) asm volatile("s_waitcnt vmcnt(8)" ::: "memory");
}

__device__ __forceinline__ void bar() {
    __builtin_amdgcn_s_barrier();
    asm volatile("" ::: "memory");
}

// ---------------- bf16 MFMA GEMM: C = A @ Bt^T + bias [+res][gelu] ----------------
// A: [MP][K] bf16 row-major. Bt: [N][K] bf16 (weights pre-transposed).
// Double-buffered gl2lds staging with counted vmcnt (never 0 mid-loop).
// BM in {32,64}: 64 -> 2x2 waves of 32x32; 32 -> 1x4 waves of 32x16.
// EPI: 1 = bias+res -> Cf; 2 = bias+gelu -> Cb;
//      3 = QKV: bias -> Cb always, -> Cf only col<512 (only Q needed in f32);
//      4 = bias+res -> Cf, hi->Cb, lo->Cb2 (split for halting GEMM)
template<int EPI, int BM>
__global__ __launch_bounds__(256)
void mgemm(const __hip_bfloat16* __restrict__ A, const __hip_bfloat16* __restrict__ Bt,
           const float* __restrict__ bias, const float* __restrict__ res,
           float* __restrict__ Cf, __hip_bfloat16* __restrict__ Cb,
           __hip_bfloat16* __restrict__ Cb2, int M, int N, int K)
{
    constexpr int ACH  = BM * 8;          // A tile 16B-chunks
    constexpr int ABYT = BM * 128;        // A tile bytes
    constexpr int STG  = ABYT + 8192;     // bytes per buffer (A + B)
    constexpr int LPT  = (ACH + 512) / 256; // gl2lds per thread per stage (4 or 3)
    constexpr int NI   = (BM == 64) ? 2 : 1;
    __shared__ char lds[2 * STG];
    const int tid = threadIdx.x;
    const int bm = blockIdx.y * BM, bn = blockIdx.x << 6;
    const int lane = tid & 63, wv = tid >> 6;
    const int wm = (BM == 64) ? ((wv & 1) << 5) : 0;
    const int wn = (BM == 64) ? ((wv >> 1) << 5) : (wv << 4);
    const int fr = lane & 15, kg = lane >> 4;

    int offA[2][2], offB[2][2];
    #pragma unroll
    for (int mi = 0; mi < 2; ++mi)
        #pragma unroll
        for (int kk = 0; kk < 2; ++kk) {
            int kb = (kk << 6) + (kg << 4);
            int ra = wm + (mi << 4) + fr;
            offA[mi][kk] = (ra << 7) + (kb ^ ((ra & 7) << 4));
        }
    #pragma unroll
    for (int ni = 0; ni < NI; ++ni)
        #pragma unroll
        for (int kk = 0; kk < 2; ++kk) {
            int kb = (kk << 6) + (kg << 4);
            int rb = wn + (ni << 4) + fr;
            offB[ni][kk] = ABYT + (rb << 7) + (kb ^ ((rb & 7) << 4));
        }

    auto stage = [&](int sb, int k0) {
        char* base = lds + sb * STG;
        #pragma unroll
        for (int c = 0; c < ACH / 256; ++c) {
            int idx = c * 256 + tid;
            int row = idx >> 3, kb = (idx & 7) << 4;
            gl2lds16((const char*)A + (((size_t)(bm + row) * K + k0) << 1) + (kb ^ ((row & 7) << 4)),
                     base + idx * 16);
        }
        #pragma unroll
        for (int c = 0; c < 2; ++c) {
            int idx = c * 256 + tid;
            int row = idx >> 3, kb = (idx & 7) << 4;
            gl2lds16((const char*)Bt + (((size_t)(bn + row) * K + k0) << 1) + (kb ^ ((row & 7) << 4)),
                     base + ABYT + idx * 16);
        }
    };

    f32x4 acc[2][2] = {};
    const int NK = K >> 6;
    stage(0, 0);
    for (int ks = 0; ks < NK; ++ks) {
        const int cur = ks & 1;
        if (ks + 1 < NK) { stage(cur ^ 1, (ks + 1) << 6); vmw<LPT>(); }
        else vmw<0>();
        bar();                               // stage ks data visible in LDS
        const char* bp = lds + cur * STG;
        bf16x8 af[2][2], bf_[2][2];
        #pragma unroll
        for (int mi = 0; mi < 2; ++mi)
            #pragma unroll
            for (int kk = 0; kk < 2; ++kk)
                af[mi][kk] = *(const bf16x8*)(bp + offA[mi][kk]);
        #pragma unroll
        for (int ni = 0; ni < NI; ++ni)
            #pragma unroll
            for (int kk = 0; kk < 2; ++kk)
                bf_[ni][kk] = *(const bf16x8*)(bp + offB[ni][kk]);
        #pragma unroll
        for (int kk = 0; kk < 2; ++kk)
            #pragma unroll
            for (int mi = 0; mi < 2; ++mi)
                #pragma unroll
                for (int ni = 0; ni < NI; ++ni)
                    acc[mi][ni] = __builtin_amdgcn_mfma_f32_16x16x32_bf16(
                        af[mi][kk], bf_[ni][kk], acc[mi][ni], 0, 0, 0);
        asm volatile("s_waitcnt lgkmcnt(0)" ::: "memory");
        bar();                               // buf[cur] reusable next+1 iter
    }

    const int rb4 = kg << 2;
    #pragma unroll
    for (int mi = 0; mi < 2; ++mi)
        #pragma unroll
        for (int ni = 0; ni < NI; ++ni) {
            const int col = bn + wn + (ni << 4) + fr;
            const float bv = bias[col];
            #pragma unroll
            for (int r = 0; r < 4; ++r) {
                const int row = bm + wm + (mi << 4) + rb4 + r;
                if (row >= M) continue;
                float v = acc[mi][ni][r] + bv;
                if (EPI == 1 || EPI == 4) v += res[(size_t)row * N + col];
                if (EPI == 2) {
                    v = 0.5f * v * (1.f + tanhf(0.7978845608028654f * (v + 0.044715f * v * v * v)));
                    Cb[(size_t)row * N + col] = __float2bfloat16(v);
                } else if (EPI == 3) {
                    if (col < 512) Cf[(size_t)row * N + col] = v;
                    Cb[(size_t)row * N + col] = __float2bfloat16(v);
                } else if (EPI == 4) {
                    Cf[(size_t)row * N + col] = v;
                    __hip_bfloat16 hi = __float2bfloat16(v);
                    Cb[(size_t)row * N + col] = hi;
                    Cb2[(size_t)row * N + col] = __float2bfloat16(v - __bfloat162float(hi));
                } else {
                    Cf[(size_t)row * N + col] = v;
                }
            }
        }
}

// ---------------- halting GEMM: z[row][0:2] += tanh(curr@Wh1+bh1) @ Wh2 ----------------
// split-bf16: acc = Ah*Bh + Ah*Bl + Al*Bh. N=K=512 fixed. BM=32, double-buffered.
__global__ __launch_bounds__(256)
void halt_gemm(const __hip_bfloat16* __restrict__ Ahp, const __hip_bfloat16* __restrict__ Alp,
               const __hip_bfloat16* __restrict__ Bhp, const __hip_bfloat16* __restrict__ Blp,
               const float* __restrict__ bh1, const float* __restrict__ Wh2,
               float* __restrict__ z, int M)
{
    constexpr int STG = 24576;   // Ah 4K @0, Al 4K @4096, Bh 8K @8192, Bl 8K @16384
    __shared__ char lds[2 * STG];
    const int tid = threadIdx.x;
    const int bm = blockIdx.y << 5, bn = blockIdx.x << 6;
    const int lane = tid & 63, wv = tid >> 6;
    const int wn = wv << 4;
    const int fr = lane & 15, kg = lane >> 4;

    int offA[2][2], offB[2];
    #pragma unroll
    for (int mi = 0; mi < 2; ++mi)
        #pragma unroll
        for (int kk = 0; kk < 2; ++kk) {
            int kb = (kk << 6) + (kg << 4);
            int ra = (mi << 4) + fr;
            offA[mi][kk] = (ra << 7) + (kb ^ ((ra & 7) << 4));
        }
    #pragma unroll
    for (int kk = 0; kk < 2; ++kk) {
        int kb = (kk << 6) + (kg << 4);
        int rb = wn + fr;
        offB[kk] = 8192 + (rb << 7) + (kb ^ ((rb & 7) << 4));
    }

    auto stage = [&](int sb, int k0) {
        char* base = lds + sb * STG;
        {
            int row = tid >> 3, kb = (tid & 7) << 4;
            int swz = kb ^ ((row & 7) << 4);
            size_t aoff = (((size_t)(bm + row) * 512 + k0) << 1) + swz;
            gl2lds16((const char*)Ahp + aoff, base + tid * 16);
            gl2lds16((const char*)Alp + aoff, base + 4096 + tid * 16);
        }
        #pragma unroll
        for (int c = 0; c < 2; ++c) {
            int idx = c * 256 + tid;
            int row = idx >> 3, kb = (idx & 7) << 4;
            int swz = kb ^ ((row & 7) << 4);
            size_t boff = (((size_t)(bn + row) * 512 + k0) << 1) + swz;
            gl2lds16((const char*)Bhp + boff, base + 8192 + idx * 16);
            gl2lds16((const char*)Blp + boff, base + 16384 + idx * 16);
        }
    };

    f32x4 acc[2] = {};
    stage(0, 0);
    for (int ks = 0; ks < 8; ++ks) {
        const int cur = ks & 1;
        if (ks < 7) { stage(cur ^ 1, (ks + 1) << 6); vmw<6>(); }
        else vmw<0>();
        bar();
        const char* bp = lds + cur * STG;
        bf16x8 ah[2][2], al[2][2], bh_[2], bl_[2];
        #pragma unroll
        for (int mi = 0; mi < 2; ++mi)
            #pragma unroll
            for (int kk = 0; kk < 2; ++kk) {
                ah[mi][kk] = *(const bf16x8*)(bp + offA[mi][kk]);
                al[mi][kk] = *(const bf16x8*)(bp + offA[mi][kk] + 4096);
            }
        #pragma unroll
        for (int kk = 0; kk < 2; ++kk) {
            bh_[kk] = *(const bf16x8*)(bp + offB[kk]);
            bl_[kk] = *(const bf16x8*)(bp + offB[kk] + 8192);
        }
        #pragma unroll
        for (int kk = 0; kk < 2; ++kk)
            #pragma unroll
            for (int mi = 0; mi < 2; ++mi) {
                acc[mi] = __builtin_amdgcn_mfma_f32_16x16x32_bf16(ah[mi][kk], bh_[kk], acc[mi], 0, 0, 0);
                acc[mi] = __builtin_amdgcn_mfma_f32_16x16x32_bf16(ah[mi][kk], bl_[kk], acc[mi], 0, 0, 0);
                acc[mi] = __builtin_amdgcn_mfma_f32_16x16x32_bf16(al[mi][kk], bh_[kk], acc[mi], 0, 0, 0);
            }
        asm volatile("s_waitcnt lgkmcnt(0)" ::: "memory");
        bar();
    }

    const int col = bn + wn + fr;
    const float b_ = bh1[col];
    const float w0_ = Wh2[col * 2 + 0];
    const float w1_ = Wh2[col * 2 + 1];
    #pragma unroll
    for (int mi = 0; mi < 2; ++mi)
        #pragma unroll
        for (int r = 0; r < 4; ++r) {
            float v = tanhf(acc[mi][r] + b_);
            float p0 = v * w0_;
            float p1 = v * w1_;
            #pragma unroll
            for (int m2 = 1; m2 < 16; m2 <<= 1) {
                p0 += __shfl_xor(p0, m2);
                p1 += __shfl_xor(p1, m2);
            }
            if (fr == 0) {
                int row = bm + (mi << 4) + (kg << 2) + r;
                if (row < M) {
                    atomicAdd(&z[row * 2 + 0], p0);
                    atomicAdd(&z[row * 2 + 1], p1);
                }
            }
        }
}

// ---------------- MFMA attention ----------------
// grid (5 q-chunks, 8 heads, 16 batch), 256 threads.
#define KT_BASE 0          // [144][128B] XOR-swizzled K (B-layout)   18432
#define VT_BASE 18432      // [64][168] bf16 V^T (stride 336B)        21504
#define QC_BASE 39936      // [32][72] bf16 q+cb (stride 144B)         4608
#define S_BASE  44544      // [32][148] f32 logits                    18944
#define P_BASE  63488      // [32][168] bf16 softmax (stride 336B)    10752
#define R_BASE  74240      // [32][8] f32 rel logits                   1024
__global__ __launch_bounds__(256)
void attn_mfma(const float* __restrict__ qkv, const __hip_bfloat16* __restrict__ qkvb,
               const float* __restrict__ rk7, const float* __restrict__ cbias,
               const float* __restrict__ rbias, __hip_bfloat16* __restrict__ aout)
{
    __shared__ char lds[75264];
    const int tid = threadIdx.x;
    const int chunk = blockIdx.x, hh = blockIdx.y, b = blockIdx.z;
    const int q0 = chunk << 5;
    const int lane = tid & 63, wv = tid >> 6;
    const int fr = lane & 15, kg = lane >> 4;
    const size_t qrow0 = (size_t)b * Sc;
    const short* qs = (const short*)qkvb;

    // zero Kt pad rows 129..143
    if (tid < 120) {
        f32x4 zz = {};
        *(f32x4*)(lds + KT_BASE + 129 * 128 + tid * 16) = zz;
    }
    // stage Kt (rows 0..128) via global_load_lds, XOR pre-swizzled source
    #pragma unroll
    for (int i = 0; i < 5; ++i) {
        int idx = i * 256 + tid;
        if (idx < 1152) {
            int row = idx >> 3, ch = idx & 7;
            if (row <= 128) {
                const char* src = (const char*)qkvb +
                    (((qrow0 + row) * 1536 + 512 + (size_t)hh * 64) << 1) + ((ch ^ (row & 7)) << 4);
                gl2lds16(src, lds + KT_BASE + idx * 16);
            }
        }
    }
    // stage V^T: Vt[d][T], zero-padded T>=129
    #pragma unroll
    for (int i = 0; i < 6; ++i) {
        int idx = i * 256 + tid;
        if (idx < 1344) {
            int d = idx / 21, g = idx % 21;
            int T0 = g * 8;
            bf16x8 pk;
            #pragma unroll
            for (int j = 0; j < 8; ++j) {
                int T = T0 + j;
                pk[j] = (T <= 128) ? qs[(qrow0 + T) * 1536 + 1024 + hh * 64 + d] : (short)0;
            }
            *(bf16x8*)(lds + VT_BASE + d * 336 + T0 * 2) = pk;
        }
    }
    // stage Qc = bf16(q + content_bias)
    #pragma unroll
    for (int i = 0; i < 8; ++i) {
        int idx = i * 256 + tid;
        int row = idx >> 6, d = idx & 63;
        float v = qkv[(qrow0 + q0 + row) * 1536 + hh * 64 + d] + cbias[hh * 64 + d];
        *(__hip_bfloat16*)(lds + QC_BASE + row * 144 + d * 2) = __float2bfloat16(v);
    }
    // R[row][c] = (q + rbias) . rk7[c]
    if (tid < 224) {
        int row = tid / 7, c = tid % 7;
        const float* qp  = qkv + (qrow0 + q0 + row) * 1536 + hh * 64;
        const float* rp  = rk7 + c * 512 + hh * 64;
        const float* rbp = rbias + hh * 64;
        float a = 0.f;
        #pragma unroll 8
        for (int d = 0; d < 64; ++d) a += (qp[d] + rbp[d]) * rp[d];
        *(float*)(lds + R_BASE + (row * 8 + c) * 4) = a;
    }
    __syncthreads();

    // QK^T: 9 N-tiles over 4 waves
    f32x4 acc[2][3] = {};
    #pragma unroll
    for (int ni = 0; ni < 3; ++ni) {
        int nt = wv + ni * 4;
        if (nt > 8) continue;
        #pragma unroll
        for (int mt = 0; mt < 2; ++mt)
            #pragma unroll
            for (int ks = 0; ks < 2; ++ks) {
                bf16x8 a = *(const bf16x8*)(lds + QC_BASE + (mt * 16 + fr) * 144 + ks * 64 + kg * 16);
                int rowb = nt * 16 + fr;
                bf16x8 bb = *(const bf16x8*)(lds + KT_BASE + rowb * 128 +
                                             ((ks * 64 + kg * 16) ^ ((rowb & 7) << 4)));
                acc[mt][ni] = __builtin_amdgcn_mfma_f32_16x16x32_bf16(a, bb, acc[mt][ni], 0, 0, 0);
            }
    }
    // S = (cl + rl)*scale, masked
    #pragma unroll
    for (int ni = 0; ni < 3; ++ni) {
        int nt = wv + ni * 4;
        if (nt > 8) continue;
        int col = nt * 16 + fr;
        #pragma unroll
        for (int mt = 0; mt < 2; ++mt)
            #pragma unroll
            for (int r = 0; r < 4; ++r) {
                int row = mt * 16 + kg * 4 + r;
                float sv;
                if (col > 128) sv = -1e30f;
                else {
                    int delta = q0 + row - col;
                    int c = delta >= 3 ? 3 : (delta <= -3 ? 4 : (delta < 0 ? delta + 7 : delta));
                    float rl = *(const float*)(lds + R_BASE + (row * 8 + c) * 4);
                    sv = (acc[mt][ni][r] + rl) * 0.125f;
                }
                *(float*)(lds + S_BASE + (row * 148 + col) * 4) = sv;
            }
    }
    __syncthreads();

    // softmax (8 rows per wave) -> P bf16
    #pragma unroll
    for (int rr = 0; rr < 8; ++rr) {
        int row = wv * 8 + rr;
        const float* srow = (const float*)(lds + S_BASE + row * 148 * 4);
        float s0 = srow[lane];
        float s1 = srow[lane + 64];
        float s2 = (lane < 16) ? srow[lane + 128] : -1e30f;
        float mx = fmaxf(fmaxf(s0, s1), s2);
        #pragma unroll
        for (int m2 = 1; m2 < 64; m2 <<= 1) mx = fmaxf(mx, __shfl_xor(mx, m2));
        float e0 = expf(s0 - mx), e1 = expf(s1 - mx);
        float e2 = (lane < 16) ? expf(s2 - mx) : 0.f;
        float sum = e0 + e1 + e2;
        #pragma unroll
        for (int m2 = 1; m2 < 64; m2 <<= 1) sum += __shfl_xor(sum, m2);
        float inv = 1.f / sum;
        __hip_bfloat16* prow = (__hip_bfloat16*)(lds + P_BASE + row * 336);
        prow[lane] = __float2bfloat16(e0 * inv);
        prow[lane + 64] = __float2bfloat16(e1 * inv);
        if (lane < 32) prow[lane + 128] = __float2bfloat16((lane < 16) ? e2 * inv : 0.f);
    }
    __syncthreads();

    // PV: wave owns 16 output dims
    f32x4 acc2[2] = {};
    #pragma unroll
    for (int mt = 0; mt < 2; ++mt)
        #pragma unroll
        for (int ks = 0; ks < 5; ++ks) {
            bf16x8 a  = *(const bf16x8*)(lds + P_BASE + (mt * 16 + fr) * 336 + ks * 64 + kg * 16);
            bf16x8 bb = *(const bf16x8*)(lds + VT_BASE + (wv * 16 + fr) * 336 + ks * 64 + kg * 16);
            acc2[mt] = __builtin_amdgcn_mfma_f32_16x16x32_bf16(a, bb, acc2[mt], 0, 0, 0);
        }
    #pragma unroll
    for (int mt = 0; mt < 2; ++mt)
        #pragma unroll
        for (int r = 0; r < 4; ++r) {
            int t = q0 + mt * 16 + kg * 4 + r;
            if (t <= 128)
                aout[(qrow0 + t) * 512 + hh * 64 + wv * 16 + fr] = __float2bfloat16(acc2[mt][r]);
        }
}

// ---------------- per-row LayerNorm -> bf16 ----------------
__global__ __launch_bounds__(256)
void ln_kernel(const float* __restrict__ in, const float* __restrict__ s,
               const float* __restrict__ o, __hip_bfloat16* __restrict__ out)
{
    int row = blockIdx.x, tid = threadIdx.x;
    const float* rp = in + (size_t)row * 512;
    float x0 = rp[tid], x1 = rp[tid + 256];
    float sum = x0 + x1, sq = x0 * x0 + x1 * x1;
    #pragma unroll
    for (int m2 = 1; m2 < 64; m2 <<= 1) { sum += __shfl_xor(sum, m2); sq += __shfl_xor(sq, m2); }
    __shared__ float ssum[4], ssq[4];
    if ((tid & 63) == 0) { ssum[tid >> 6] = sum; ssq[tid >> 6] = sq; }
    __syncthreads();
    float tot = ssum[0] + ssum[1] + ssum[2] + ssum[3];
    float totq = ssq[0] + ssq[1] + ssq[2] + ssq[3];
    float mean = tot * (1.f / 512.f);
    float inv = rsqrtf(totq * (1.f / 512.f) - mean * mean + EPSLN);
    out[(size_t)row * 512 + tid] = __float2bfloat16((x0 - mean) * inv * s[tid] + o[tid]);
    out[(size_t)row * 512 + tid + 256] = __float2bfloat16((x1 - mean) * inv * s[tid + 256] + o[tid + 256]);
}

// ---------------- ACT bookkeeping + LN(curr) + blend + h_out ----------------
__global__ __launch_bounds__(256)
void haltblend(const float* __restrict__ curr, const float* __restrict__ s,
               const float* __restrict__ o, float* __restrict__ zbuf,
               float* __restrict__ lanh, float* __restrict__ lah,
               float* __restrict__ h, __hip_bfloat16* __restrict__ hb,
               float* __restrict__ hout)
{
    int row = blockIdx.x, tid = threadIdx.x;
    float z0 = zbuf[row * 2 + 0] + 2.f;
    float z1 = zbuf[row * 2 + 1] - 2.f;
    float mxz = fmaxf(z0, z1);
    float lse = mxz + logf(expf(z0 - mxz) + expf(z1 - mxz));
    float lg0 = z0 - lse, lg1 = z1 - lse;
    float ln_ = lanh[row], la_ = lah[row];
    float lhalt = ln_ + lg1;
    float hl = expf(la_);            // PRE-update lah
    float ph = expf(lhalt);

    const float* rp = curr + (size_t)row * 512;
    float x0 = rp[tid], x1 = rp[tid + 256];
    float sum = x0 + x1, sq = x0 * x0 + x1 * x1;
    #pragma unroll
    for (int m2 = 1; m2 < 64; m2 <<= 1) { sum += __shfl_xor(sum, m2); sq += __shfl_xor(sq, m2); }
    __shared__ float ssum[4], ssq[4];
    if ((tid & 63) == 0) { ssum[tid >> 6] = sum; ssq[tid >> 6] = sq; }
    __syncthreads();
    float tot = ssum[0] + ssum[1] + ssum[2] + ssum[3];
    float totq = ssq[0] + ssq[1] + ssq[2] + ssq[3];
    float mean = tot * (1.f / 512.f);
    float inv = rsqrtf(totq * (1.f / 512.f) - mean * mean + EPSLN);

    if (tid == 0) {
        lanh[row] = ln_ + lg0;
        float m3 = fmaxf(la_, lhalt);
        lah[row] = m3 + logf(expf(la_ - m3) + expf(lhalt - m3));
        zbuf[row * 2 + 0] = 0.f;
        zbuf[row * 2 + 1] = 0.f;
    }

    float cl0 = (x0 - mean) * inv * s[tid] + o[tid];
    float cl1 = (x1 - mean) * inv * s[tid + 256] + o[tid + 256];
    size_t i0 = (size_t)row * 512 + tid;
    float h0n = hl * h[i0] + (1.f - hl) * cl0;
    float h1n = hl * h[i0 + 256] + (1.f - hl) * cl1;
    h[i0] = h0n; h[i0 + 256] = h1n;
    hb[i0] = __float2bfloat16(h0n); hb[i0 + 256] = __float2bfloat16(h1n);
    hout[i0] += ph * cl0;
    hout[i0 + 256] += ph * cl1;
}

// ---------------- setup kernels ----------------
__global__ __launch_bounds__(256)
void emb_kernel(const float* __restrict__ x, const float* __restrict__ We,
                const float* __restrict__ eos, const float* __restrict__ s,
                const float* __restrict__ o, float* __restrict__ h,
                __hip_bfloat16* __restrict__ hb)
{
    int row = blockIdx.x, tid = threadIdx.x;
    int b = row / Sc, t = row % Sc;
    __shared__ float xs[64];
    if (t != 128 && tid < 64) xs[tid] = x[((size_t)b * 128 + t) * 64 + tid];
    __syncthreads();
    float v0, v1;
    if (t == 128) {
        v0 = eos[tid]; v1 = eos[tid + 256];
    } else {
        v0 = 0.f; v1 = 0.f;
        #pragma unroll 8
        for (int k = 0; k < 64; ++k) {
            float xv = xs[k];
            v0 = fmaf(xv, We[k * 512 + tid], v0);
            v1 = fmaf(xv, We[k * 512 + tid + 256], v1);
        }
    }
    float sum = v0 + v1, sq = v0 * v0 + v1 * v1;
    #pragma unroll
    for (int m2 = 1; m2 < 64; m2 <<= 1) { sum += __shfl_xor(sum, m2); sq += __shfl_xor(sq, m2); }
    __shared__ float ssum[4], ssq[4];
    if ((tid & 63) == 0) { ssum[tid >> 6] = sum; ssq[tid >> 6] = sq; }
    __syncthreads();
    float tot = ssum[0] + ssum[1] + ssum[2] + ssum[3];
    float totq = ssq[0] + ssq[1] + ssq[2] + ssq[3];
    float mean = tot * (1.f / 512.f);
    float inv = rsqrtf(totq * (1.f / 512.f) - mean * mean + EPSLN);
    float h0 = (v0 - mean) * inv * s[tid] + o[tid];
    float h1 = (v1 - mean) * inv * s[tid + 256] + o[tid + 256];
    h[(size_t)row * 512 + tid] = h0;
    h[(size_t)row * 512 + tid + 256] = h1;
    hb[(size_t)row * 512 + tid] = __float2bfloat16(h0);
    hb[(size_t)row * 512 + tid + 256] = __float2bfloat16(h1);
}

__global__ __launch_bounds__(256)
void rk7_kernel(const float* __restrict__ pos, const float* __restrict__ Wk,
                const float* __restrict__ bk, float* __restrict__ rk7)
{
    int c = blockIdx.x, tid = threadIdx.x;
    __shared__ float ps[512];
    ps[tid] = pos[c * 512 + tid];
    ps[tid + 256] = pos[c * 512 + tid + 256];
    __syncthreads();
    float a0 = bk[tid], a1 = bk[tid + 256];
    for (int k = 0; k < 512; ++k) {
        float pv = ps[k];
        a0 = fmaf(pv, Wk[(size_t)k * 512 + tid], a0);
        a1 = fmaf(pv, Wk[(size_t)k * 512 + tid + 256], a1);
    }
    rk7[c * 512 + tid] = a0;
    rk7[c * 512 + tid + 256] = a1;
}

__global__ __launch_bounds__(256)
void pack_qkvT(const float* __restrict__ Wq, const float* __restrict__ Wk,
               const float* __restrict__ Wv, __hip_bfloat16* __restrict__ Wt)
{
    int idx = blockIdx.x * 256 + threadIdx.x;
    if (idx >= 1536 * 512) return;
    int n = idx >> 9, k = idx & 511;
    const float* src = (n < 512) ? Wq : (n < 1024) ? Wk : Wv;
    int nc = n & 511;
    Wt[idx] = __float2bfloat16(src[(size_t)k * 512 + nc]);
}

__global__ __launch_bounds__(256)
void transposeT(const float* __restrict__ W, __hip_bfloat16* __restrict__ Wt, int K, int N)
{
    int idx = blockIdx.x * 256 + threadIdx.x;
    if (idx >= K * N) return;
    int n = idx / K, k = idx - n * K;
    Wt[idx] = __float2bfloat16(W[(size_t)k * N + n]);
}

__global__ __launch_bounds__(256)
void transposeT_split(const float* __restrict__ W, __hip_bfloat16* __restrict__ Whi,
                      __hip_bfloat16* __restrict__ Wlo, int K, int N)
{
    int idx = blockIdx.x * 256 + threadIdx.x;
    if (idx >= K * N) return;
    int n = idx / K, k = idx - n * K;
    float v = W[(size_t)k * N + n];
    __hip_bfloat16 hi = __float2bfloat16(v);
    Whi[idx] = hi;
    Wlo[idx] = __float2bfloat16(v - __bfloat162float(hi));
}

__global__ __launch_bounds__(256)
void pack_bias(const float* __restrict__ bq, const float* __restrict__ bk,
               const float* __restrict__ bv, float* __restrict__ bqkv)
{
    int idx = blockIdx.x * 256 + threadIdx.x;
    if (idx < 1536)
        bqkv[idx] = (idx < 512) ? bq[idx] : (idx < 1024) ? bk[idx - 512] : bv[idx - 1024];
}

__global__ __launch_bounds__(256)
void init_kernel(float* __restrict__ lanh, float* __restrict__ lah, float* __restrict__ zbuf)
{
    int idx = blockIdx.x * 256 + threadIdx.x;
    if (idx < Mc) {
        lanh[idx] = 0.f; lah[idx] = -64.f;
        zbuf[idx * 2 + 0] = 0.f; zbuf[idx * 2 + 1] = 0.f;
    }
}

// ---------------- host launcher ----------------
extern "C" void kernel_launch(void* const* d_in, const int* in_sizes, int n_in,
                              void* d_out, int out_size, void* d_ws, size_t ws_size,
                              hipStream_t stream)
{
    const float* x     = (const float*)d_in[0];
    const float* We    = (const float*)d_in[1];
    const float* eos   = (const float*)d_in[2];
    const float* Wq    = (const float*)d_in[3];
    const float* bq    = (const float*)d_in[4];
    const float* Wk    = (const float*)d_in[5];
    const float* bk    = (const float*)d_in[6];
    const float* Wv    = (const float*)d_in[7];
    const float* bv    = (const float*)d_in[8];
    const float* Wo    = (const float*)d_in[9];
    const float* bo    = (const float*)d_in[10];
    const float* cbias = (const float*)d_in[11];
    const float* rbias = (const float*)d_in[12];
    const float* pos   = (const float*)d_in[13];
    const float* ln2s  = (const float*)d_in[14];
    const float* ln2o  = (const float*)d_in[15];
    const float* lnos  = (const float*)d_in[16];
    const float* lnoo  = (const float*)d_in[17];
    const float* W1    = (const float*)d_in[18];
    const float* b1    = (const float*)d_in[19];
    const float* W2    = (const float*)d_in[20];
    const float* b2    = (const float*)d_in[21];
    const float* Wh1   = (const float*)d_in[22];
    const float* bh1   = (const float*)d_in[23];
    const float* Wh2   = (const float*)d_in[24];
    (void)in_sizes; (void)n_in; (void)ws_size;

    char* wp = (char*)d_ws;
    auto alloc = [&](size_t bytes) { char* p = wp; wp += (bytes + 255) & ~(size_t)255; return p; };
    float*          h     = (float*)alloc((size_t)MP * 512 * 4);
    __hip_bfloat16* hb    = (__hip_bfloat16*)alloc((size_t)MP * 512 * 2);
    float*          qkv   = (float*)alloc((size_t)MP * 1536 * 4);
    __hip_bfloat16* qkvb  = (__hip_bfloat16*)alloc((size_t)MP * 1536 * 2);
    __hip_bfloat16* abufb = (__hip_bfloat16*)alloc((size_t)MP * 512 * 2);
    float*          hmid  = (float*)alloc((size_t)MP * 512 * 4);
    __hip_bfloat16* hnb   = (__hip_bfloat16*)alloc((size_t)MP * 512 * 2);
    __hip_bfloat16* g1b   = (__hip_bfloat16*)alloc((size_t)MP * 1024 * 2);
    float*          curr  = (float*)alloc((size_t)MP * 512 * 4);
    __hip_bfloat16* chi   = (__hip_bfloat16*)alloc((size_t)MP * 512 * 2);
    __hip_bfloat16* clo   = (__hip_bfloat16*)alloc((size_t)MP * 512 * 2);
    __hip_bfloat16* WqkvT = (__hip_bfloat16*)alloc((size_t)1536 * 512 * 2);
    __hip_bfloat16* WoT   = (__hip_bfloat16*)alloc((size_t)512 * 512 * 2);
    __hip_bfloat16* W1T   = (__hip_bfloat16*)alloc((size_t)1024 * 512 * 2);
    __hip_bfloat16* W2T   = (__hip_bfloat16*)alloc((size_t)512 * 1024 * 2);
    __hip_bfloat16* Wh1Th = (__hip_bfloat16*)alloc((size_t)512 * 512 * 2);
    __hip_bfloat16* Wh1Tl = (__hip_bfloat16*)alloc((size_t)512 * 512 * 2);
    float*          bqkv  = (float*)alloc(1536 * 4);
    float*          rk7   = (float*)alloc(7 * 512 * 4);
    float*          lanh  = (float*)alloc(Mc * 4);
    float*          lah   = (float*)alloc(Mc * 4);
    float*          zbuf  = (float*)alloc((size_t)Mc * 2 * 4);
    float* hout = (float*)d_out;

    hipMemsetAsync(d_out, 0, (size_t)out_size * sizeof(float), stream);
    init_kernel<<<(Mc + 255) / 256, 256, 0, stream>>>(lanh, lah, zbuf);
    pack_qkvT<<<(1536 * 512 + 255) / 256, 256, 0, stream>>>(Wq, Wk, Wv, WqkvT);
    transposeT<<<(512 * 512 + 255) / 256, 256, 0, stream>>>(Wo, WoT, 512, 512);
    transposeT<<<(512 * 1024 + 255) / 256, 256, 0, stream>>>(W1, W1T, 512, 1024);
    transposeT<<<(1024 * 512 + 255) / 256, 256, 0, stream>>>(W2, W2T, 1024, 512);
    transposeT_split<<<(512 * 512 + 255) / 256, 256, 0, stream>>>(Wh1, Wh1Th, Wh1Tl, 512, 512);
    pack_bias<<<(1536 + 255) / 256, 256, 0, stream>>>(bq, bk, bv, bqkv);
    rk7_kernel<<<7, 256, 0, stream>>>(pos, Wk, bk, rk7);
    emb_kernel<<<Mc, 256, 0, stream>>>(x, We, eos, lnos, lnoo, h, hb);

    for (int it = 0; it < ITERS; ++it) {
        mgemm<3, 64><<<dim3(24, 33), 256, 0, stream>>>(hb, WqkvT, bqkv, nullptr, qkv, qkvb, nullptr, Mc, 1536, 512);
        attn_mfma<<<dim3(5, 8, 16), 256, 0, stream>>>(qkv, qkvb, rk7, cbias, rbias, abufb);
        mgemm<1, 32><<<dim3(8, 66), 256, 0, stream>>>(abufb, WoT, bo, h, hmid, nullptr, nullptr, Mc, 512, 512);
        ln_kernel<<<Mc, 256, 0, stream>>>(hmid, ln2s, ln2o, hnb);
        mgemm<2, 32><<<dim3(16, 66), 256, 0, stream>>>(hnb, W1T, b1, nullptr, nullptr, g1b, nullptr, Mc, 1024, 512);
        mgemm<4, 32><<<dim3(8, 66), 256, 0, stream>>>(g1b, W2T, b2, hmid, curr, chi, clo, Mc, 512, 1024);
        halt_gemm<<<dim3(8, 66), 256, 0, stream>>>(chi, clo, Wh1Th, Wh1Tl, bh1, Wh2, zbuf, Mc);
        haltblend<<<Mc, 256, 0, stream>>>(curr, lnos, lnoo, zbuf, lanh, lah, h, hb, hout);
    }
}

// Round 3
// 12605.819 us; speedup vs baseline: 1.4799x; 1.0797x over previous
//
#include <hip/hip_runtime.h>
#include <hip/hip_bf16.h>
#include <cstdint>
#include <cmath>

#define EPSLN 1e-5f

typedef __attribute__((ext_vector_type(8))) short bf16x8;
typedef __attribute__((ext_vector_type(4))) float f32x4;

constexpr int Bc = 16;
constexpr int Sc = 129;          // T+1
constexpr int Mc = Bc * Sc;      // 2064 rows (real)
constexpr int MP = 2112;         // padded rows = 33*64 = 66*32
constexpr int ITERS = 127;       // T-1

__device__ __forceinline__ void gl2lds16(const void* g, void* l) {
    __builtin_amdgcn_global_load_lds(
        (const __attribute__((address_space(1))) unsigned int*)g,
        (__attribute__((address_space(3))) unsigned int*)l, 16, 0, 0);
}

template<int N> __device__ __forceinline__ void vmw() {
    if constexpr (N == 0) asm volatile("s_waitcnt vmcnt(0)" ::: "memory");
    else if constexpr (N == 3) asm volatile("s_waitcnt vmcnt(3)" ::: "memory");
    else if constexpr (N == 4) asm volatile("s_waitcnt vmcnt(4)" ::: "memory");
    else if constexpr (N == 6) asm volatile("s_waitcnt vmcnt(6)" ::: "memory");
}

__device__ __forceinline__ void bar() {
    __builtin_amdgcn_s_barrier();
    asm volatile("" ::: "memory");
}

__device__ __forceinline__ float bf2f(short s) {
    __hip_bfloat16 h;
    *reinterpret_cast<short*>(&h) = s;
    return __bfloat162float(h);
}
__device__ __forceinline__ short f2bf(float f) {
    __hip_bfloat16 h = __float2bfloat16(f);
    return *reinterpret_cast<short*>(&h);
}

// ---------------- bf16 MFMA GEMM: C = A @ Bt^T + epilogue ----------------
// A: [MP][K] bf16 row-major. Bt: [N][K] bf16 (weights pre-transposed).
// Double-buffered gl2lds staging with counted vmcnt (never 0 mid-loop).
// BM in {32,64}: 64 -> 2x2 waves of 32x32; 32 -> 1x4 waves of 32x16.
// EPI: 1 = bias -> Cf
//      3 = QKV: bias -> Cb (bf16 only)
//      4 = bias+res -> Cf, hi->Cb, lo->Cb2 (split for halting GEMM)
//      5 = bias+res -> Cf(f32) AND Cb(bf16) + per-row (sum,sumsq) atomics -> stats
//      6 = epilogue-LN + gelu -> Cb:  v = rinv*acc - mean*rinv*aux[col] + bias[col]
template<int EPI, int BM>
__global__ __launch_bounds__(256)
void mgemm(const __hip_bfloat16* __restrict__ A, const __hip_bfloat16* __restrict__ Bt,
           const float* __restrict__ bias, const float* __restrict__ res,
           float* __restrict__ Cf, __hip_bfloat16* __restrict__ Cb,
           __hip_bfloat16* __restrict__ Cb2, float* __restrict__ stats,
           const float* __restrict__ aux, int M, int N, int K)
{
    constexpr int ACH  = BM * 8;          // A tile 16B-chunks
    constexpr int ABYT = BM * 128;        // A tile bytes
    constexpr int STG  = ABYT + 8192;     // bytes per buffer (A + B)
    constexpr int LPT  = (ACH + 512) / 256; // gl2lds per thread per stage (4 or 3)
    constexpr int NI   = (BM == 64) ? 2 : 1;
    __shared__ char lds[2 * STG];
    const int tid = threadIdx.x;
    const int bm = blockIdx.y * BM, bn = blockIdx.x << 6;
    const int lane = tid & 63, wv = tid >> 6;
    const int wm = (BM == 64) ? ((wv & 1) << 5) : 0;
    const int wn = (BM == 64) ? ((wv >> 1) << 5) : (wv << 4);
    const int fr = lane & 15, kg = lane >> 4;

    int offA[2][2], offB[2][2];
    #pragma unroll
    for (int mi = 0; mi < 2; ++mi)
        #pragma unroll
        for (int kk = 0; kk < 2; ++kk) {
            int kb = (kk << 6) + (kg << 4);
            int ra = wm + (mi << 4) + fr;
            offA[mi][kk] = (ra << 7) + (kb ^ ((ra & 7) << 4));
        }
    #pragma unroll
    for (int ni = 0; ni < NI; ++ni)
        #pragma unroll
        for (int kk = 0; kk < 2; ++kk) {
            int kb = (kk << 6) + (kg << 4);
            int rb = wn + (ni << 4) + fr;
            offB[ni][kk] = ABYT + (rb << 7) + (kb ^ ((rb & 7) << 4));
        }

    auto stage = [&](int sb, int k0) {
        char* base = lds + sb * STG;
        #pragma unroll
        for (int c = 0; c < ACH / 256; ++c) {
            int idx = c * 256 + tid;
            int row = idx >> 3, kb = (idx & 7) << 4;
            gl2lds16((const char*)A + (((size_t)(bm + row) * K + k0) << 1) + (kb ^ ((row & 7) << 4)),
                     base + idx * 16);
        }
        #pragma unroll
        for (int c = 0; c < 2; ++c) {
            int idx = c * 256 + tid;
            int row = idx >> 3, kb = (idx & 7) << 4;
            gl2lds16((const char*)Bt + (((size_t)(bn + row) * K + k0) << 1) + (kb ^ ((row & 7) << 4)),
                     base + ABYT + idx * 16);
        }
    };

    f32x4 acc[2][2] = {};
    const int NK = K >> 6;
    stage(0, 0);
    for (int ks = 0; ks < NK; ++ks) {
        const int cur = ks & 1;
        if (ks + 1 < NK) { stage(cur ^ 1, (ks + 1) << 6); vmw<LPT>(); }
        else vmw<0>();
        bar();                               // stage ks data visible in LDS
        const char* bp = lds + cur * STG;
        bf16x8 af[2][2], bf_[2][2];
        #pragma unroll
        for (int mi = 0; mi < 2; ++mi)
            #pragma unroll
            for (int kk = 0; kk < 2; ++kk)
                af[mi][kk] = *(const bf16x8*)(bp + offA[mi][kk]);
        #pragma unroll
        for (int ni = 0; ni < NI; ++ni)
            #pragma unroll
            for (int kk = 0; kk < 2; ++kk)
                bf_[ni][kk] = *(const bf16x8*)(bp + offB[ni][kk]);
        #pragma unroll
        for (int kk = 0; kk < 2; ++kk)
            #pragma unroll
            for (int mi = 0; mi < 2; ++mi)
                #pragma unroll
                for (int ni = 0; ni < NI; ++ni)
                    acc[mi][ni] = __builtin_amdgcn_mfma_f32_16x16x32_bf16(
                        af[mi][kk], bf_[ni][kk], acc[mi][ni], 0, 0, 0);
        asm volatile("s_waitcnt lgkmcnt(0)" ::: "memory");
        bar();                               // buf[cur] reusable next+1 iter
    }

    const int rb4 = kg << 2;
    float b_[NI], w_[NI];
    #pragma unroll
    for (int ni = 0; ni < NI; ++ni) {
        int col = bn + wn + (ni << 4) + fr;
        b_[ni] = bias[col];
        if (EPI == 6) w_[ni] = aux[col];
    }
    #pragma unroll
    for (int mi = 0; mi < 2; ++mi)
        #pragma unroll
        for (int r = 0; r < 4; ++r) {
            const int row = bm + wm + (mi << 4) + rb4 + r;
            if (row >= M) continue;          // uniform over fr-group
            float mean = 0.f, rinv = 0.f;
            if (EPI == 6) {
                float s0 = stats[row * 2 + 0], s1 = stats[row * 2 + 1];
                mean = s0 * (1.f / 512.f);
                rinv = rsqrtf(s1 * (1.f / 512.f) - mean * mean + EPSLN);
            }
            float vs = 0.f, vq = 0.f;
            #pragma unroll
            for (int ni = 0; ni < NI; ++ni) {
                const int col = bn + wn + (ni << 4) + fr;
                float v = acc[mi][ni][r];
                if (EPI == 6) v = rinv * v - mean * rinv * w_[ni] + b_[ni];
                else v += b_[ni];
                if (EPI == 4 || EPI == 5) v += res[(size_t)row * N + col];
                if (EPI == 6) {
                    float g = 0.5f * v * (1.f + tanhf(0.7978845608028654f * (v + 0.044715f * v * v * v)));
                    Cb[(size_t)row * N + col] = __float2bfloat16(g);
                } else if (EPI == 3) {
                    Cb[(size_t)row * N + col] = __float2bfloat16(v);
                } else if (EPI == 4) {
                    Cf[(size_t)row * N + col] = v;
                    __hip_bfloat16 hi = __float2bfloat16(v);
                    Cb[(size_t)row * N + col] = hi;
                    Cb2[(size_t)row * N + col] = __float2bfloat16(v - __bfloat162float(hi));
                } else if (EPI == 5) {
                    Cf[(size_t)row * N + col] = v;
                    Cb[(size_t)row * N + col] = __float2bfloat16(v);
                    vs += v; vq += v * v;
                } else {
                    Cf[(size_t)row * N + col] = v;
                }
            }
            if (EPI == 5) {
                #pragma unroll
                for (int m2 = 1; m2 < 16; m2 <<= 1) {
                    vs += __shfl_xor(vs, m2);
                    vq += __shfl_xor(vq, m2);
                }
                if (fr == 0) {
                    atomicAdd(&stats[row * 2 + 0], vs);
                    atomicAdd(&stats[row * 2 + 1], vq);
                }
            }
        }
}

// ---------------- halting GEMM: z[row][0:2] += tanh(curr@Wh1+bh1) @ Wh2 ----------------
// split-bf16: acc = Ah*Bh + Ah*Bl + Al*Bh. N=K=512 fixed. BM=32, double-buffered.
__global__ __launch_bounds__(256)
void halt_gemm(const __hip_bfloat16* __restrict__ Ahp, const __hip_bfloat16* __restrict__ Alp,
               const __hip_bfloat16* __restrict__ Bhp, const __hip_bfloat16* __restrict__ Blp,
               const float* __restrict__ bh1, const float* __restrict__ Wh2,
               float* __restrict__ z, int M)
{
    constexpr int STG = 24576;   // Ah 4K @0, Al 4K @4096, Bh 8K @8192, Bl 8K @16384
    __shared__ char lds[2 * STG];
    const int tid = threadIdx.x;
    const int bm = blockIdx.y << 5, bn = blockIdx.x << 6;
    const int lane = tid & 63, wv = tid >> 6;
    const int wn = wv << 4;
    const int fr = lane & 15, kg = lane >> 4;

    int offA[2][2], offB[2];
    #pragma unroll
    for (int mi = 0; mi < 2; ++mi)
        #pragma unroll
        for (int kk = 0; kk < 2; ++kk) {
            int kb = (kk << 6) + (kg << 4);
            int ra = (mi << 4) + fr;
            offA[mi][kk] = (ra << 7) + (kb ^ ((ra & 7) << 4));
        }
    #pragma unroll
    for (int kk = 0; kk < 2; ++kk) {
        int kb = (kk << 6) + (kg << 4);
        int rb = wn + fr;
        offB[kk] = 8192 + (rb << 7) + (kb ^ ((rb & 7) << 4));
    }

    auto stage = [&](int sb, int k0) {
        char* base = lds + sb * STG;
        {
            int row = tid >> 3, kb = (tid & 7) << 4;
            int swz = kb ^ ((row & 7) << 4);
            size_t aoff = (((size_t)(bm + row) * 512 + k0) << 1) + swz;
            gl2lds16((const char*)Ahp + aoff, base + tid * 16);
            gl2lds16((const char*)Alp + aoff, base + 4096 + tid * 16);
        }
        #pragma unroll
        for (int c = 0; c < 2; ++c) {
            int idx = c * 256 + tid;
            int row = idx >> 3, kb = (idx & 7) << 4;
            int swz = kb ^ ((row & 7) << 4);
            size_t boff = (((size_t)(bn + row) * 512 + k0) << 1) + swz;
            gl2lds16((const char*)Bhp + boff, base + 8192 + idx * 16);
            gl2lds16((const char*)Blp + boff, base + 16384 + idx * 16);
        }
    };

    f32x4 acc[2] = {};
    stage(0, 0);
    for (int ks = 0; ks < 8; ++ks) {
        const int cur = ks & 1;
        if (ks < 7) { stage(cur ^ 1, (ks + 1) << 6); vmw<6>(); }
        else vmw<0>();
        bar();
        const char* bp = lds + cur * STG;
        bf16x8 ah[2][2], al[2][2], bh_[2], bl_[2];
        #pragma unroll
        for (int mi = 0; mi < 2; ++mi)
            #pragma unroll
            for (int kk = 0; kk < 2; ++kk) {
                ah[mi][kk] = *(const bf16x8*)(bp + offA[mi][kk]);
                al[mi][kk] = *(const bf16x8*)(bp + offA[mi][kk] + 4096);
            }
        #pragma unroll
        for (int kk = 0; kk < 2; ++kk) {
            bh_[kk] = *(const bf16x8*)(bp + offB[kk]);
            bl_[kk] = *(const bf16x8*)(bp + offB[kk] + 8192);
        }
        #pragma unroll
        for (int kk = 0; kk < 2; ++kk)
            #pragma unroll
            for (int mi = 0; mi < 2; ++mi) {
                acc[mi] = __builtin_amdgcn_mfma_f32_16x16x32_bf16(ah[mi][kk], bh_[kk], acc[mi], 0, 0, 0);
                acc[mi] = __builtin_amdgcn_mfma_f32_16x16x32_bf16(ah[mi][kk], bl_[kk], acc[mi], 0, 0, 0);
                acc[mi] = __builtin_amdgcn_mfma_f32_16x16x32_bf16(al[mi][kk], bh_[kk], acc[mi], 0, 0, 0);
            }
        asm volatile("s_waitcnt lgkmcnt(0)" ::: "memory");
        bar();
    }

    const int col = bn + wn + fr;
    const float b_ = bh1[col];
    const float w0_ = Wh2[col * 2 + 0];
    const float w1_ = Wh2[col * 2 + 1];
    #pragma unroll
    for (int mi = 0; mi < 2; ++mi)
        #pragma unroll
        for (int r = 0; r < 4; ++r) {
            float v = tanhf(acc[mi][r] + b_);
            float p0 = v * w0_;
            float p1 = v * w1_;
            #pragma unroll
            for (int m2 = 1; m2 < 16; m2 <<= 1) {
                p0 += __shfl_xor(p0, m2);
                p1 += __shfl_xor(p1, m2);
            }
            if (fr == 0) {
                int row = bm + (mi << 4) + (kg << 2) + r;
                if (row < M) {
                    atomicAdd(&z[row * 2 + 0], p0);
                    atomicAdd(&z[row * 2 + 1], p1);
                }
            }
        }
}

// ---------------- MFMA attention ----------------
// grid (5 q-chunks, 8 heads, 16 batch), 256 threads. All inputs read from bf16 qkvb.
#define KT_BASE 0          // [144][128B] XOR-swizzled K (B-layout)   18432
#define VT_BASE 18432      // [64][168] bf16 V^T (stride 336B)        21504
#define QC_BASE 39936      // [32][72] bf16 q+cb (stride 144B)         4608
#define S_BASE  44544      // [32][148] f32 logits                    18944
#define P_BASE  63488      // [32][168] bf16 softmax (stride 336B)    10752
#define R_BASE  74240      // [32][8] f32 rel logits                   1024
__global__ __launch_bounds__(256)
void attn_mfma(const __hip_bfloat16* __restrict__ qkvb,
               const float* __restrict__ rk7, const float* __restrict__ cbias,
               const float* __restrict__ rbias, __hip_bfloat16* __restrict__ aout)
{
    __shared__ char lds[75264];
    const int tid = threadIdx.x;
    const int chunk = blockIdx.x, hh = blockIdx.y, b = blockIdx.z;
    const int q0 = chunk << 5;
    const int lane = tid & 63, wv = tid >> 6;
    const int fr = lane & 15, kg = lane >> 4;
    const size_t qrow0 = (size_t)b * Sc;
    const short* qs = (const short*)qkvb;

    // zero Kt pad rows 129..143
    if (tid < 120) {
        f32x4 zz = {};
        *(f32x4*)(lds + KT_BASE + 129 * 128 + tid * 16) = zz;
    }
    // stage Kt (rows 0..128) via global_load_lds, XOR pre-swizzled source
    #pragma unroll
    for (int i = 0; i < 5; ++i) {
        int idx = i * 256 + tid;
        if (idx < 1152) {
            int row = idx >> 3, ch = idx & 7;
            if (row <= 128) {
                const char* src = (const char*)qkvb +
                    (((qrow0 + row) * 1536 + 512 + (size_t)hh * 64) << 1) + ((ch ^ (row & 7)) << 4);
                gl2lds16(src, lds + KT_BASE + idx * 16);
            }
        }
    }
    // stage V^T: Vt[d][T] stride 336B; vectorized loads along d, LDS scatter-transpose.
    // idx = T*8 + g : T in 0..167 (>=129 zero), g = d-group of 8
    #pragma unroll
    for (int i = 0; i < 6; ++i) {
        int idx = i * 256 + tid;
        if (idx < 1344) {
            int T = idx >> 3, g = idx & 7;
            if (T <= 128) {
                bf16x8 v = *(const bf16x8*)(qs + (qrow0 + T) * 1536 + 1024 + hh * 64 + g * 8);
                #pragma unroll
                for (int j = 0; j < 8; ++j)
                    *(short*)(lds + VT_BASE + (g * 8 + j) * 336 + T * 2) = v[j];
            } else {
                #pragma unroll
                for (int j = 0; j < 8; ++j)
                    *(short*)(lds + VT_BASE + (g * 8 + j) * 336 + T * 2) = (short)0;
            }
        }
    }
    // stage Qc = bf16(q + content_bias): 256 threads = 32 rows x 8 groups
    {
        int row = tid >> 3, g = tid & 7;
        bf16x8 q8 = *(const bf16x8*)(qs + (qrow0 + q0 + row) * 1536 + hh * 64 + g * 8);
        const float* cb = cbias + hh * 64 + g * 8;
        bf16x8 o8;
        #pragma unroll
        for (int j = 0; j < 8; ++j)
            o8[j] = f2bf(bf2f(q8[j]) + cb[j]);
        *(bf16x8*)(lds + QC_BASE + row * 144 + g * 16) = o8;
    }
    // R[row][c] = (q + rbias) . rk7[c], bf16 q loads vectorized
    if (tid < 224) {
        int row = tid / 7, c = tid % 7;
        const short* qp = qs + (qrow0 + q0 + row) * 1536 + hh * 64;
        const float* rp  = rk7 + c * 512 + hh * 64;
        const float* rbp = rbias + hh * 64;
        float a = 0.f;
        #pragma unroll
        for (int g = 0; g < 8; ++g) {
            bf16x8 q8 = *(const bf16x8*)(qp + g * 8);
            #pragma unroll
            for (int j = 0; j < 8; ++j)
                a += (bf2f(q8[j]) + rbp[g * 8 + j]) * rp[g * 8 + j];
        }
        *(float*)(lds + R_BASE + (row * 8 + c) * 4) = a;
    }
    __syncthreads();

    // QK^T: 9 N-tiles over 4 waves
    f32x4 acc[2][3] = {};
    #pragma unroll
    for (int ni = 0; ni < 3; ++ni) {
        int nt = wv + ni * 4;
        if (nt > 8) continue;
        #pragma unroll
        for (int mt = 0; mt < 2; ++mt)
            #pragma unroll
            for (int ks = 0; ks < 2; ++ks) {
                bf16x8 a = *(const bf16x8*)(lds + QC_BASE + (mt * 16 + fr) * 144 + ks * 64 + kg * 16);
                int rowb = nt * 16 + fr;
                bf16x8 bb = *(const bf16x8*)(lds + KT_BASE + rowb * 128 +
                                             ((ks * 64 + kg * 16) ^ ((rowb & 7) << 4)));
                acc[mt][ni] = __builtin_amdgcn_mfma_f32_16x16x32_bf16(a, bb, acc[mt][ni], 0, 0, 0);
            }
    }
    // S = (cl + rl)*scale, masked
    #pragma unroll
    for (int ni = 0; ni < 3; ++ni) {
        int nt = wv + ni * 4;
        if (nt > 8) continue;
        int col = nt * 16 + fr;
        #pragma unroll
        for (int mt = 0; mt < 2; ++mt)
            #pragma unroll
            for (int r = 0; r < 4; ++r) {
                int row = mt * 16 + kg * 4 + r;
                float sv;
                if (col > 128) sv = -1e30f;
                else {
                    int delta = q0 + row - col;
                    int c = delta >= 3 ? 3 : (delta <= -3 ? 4 : (delta < 0 ? delta + 7 : delta));
                    float rl = *(const float*)(lds + R_BASE + (row * 8 + c) * 4);
                    sv = (acc[mt][ni][r] + rl) * 0.125f;
                }
                *(float*)(lds + S_BASE + (row * 148 + col) * 4) = sv;
            }
    }
    __syncthreads();

    // softmax (8 rows per wave) -> P bf16
    #pragma unroll
    for (int rr = 0; rr < 8; ++rr) {
        int row = wv * 8 + rr;
        const float* srow = (const float*)(lds + S_BASE + row * 148 * 4);
        float s0 = srow[lane];
        float s1 = srow[lane + 64];
        float s2 = (lane < 16) ? srow[lane + 128] : -1e30f;
        float mx = fmaxf(fmaxf(s0, s1), s2);
        #pragma unroll
        for (int m2 = 1; m2 < 64; m2 <<= 1) mx = fmaxf(mx, __shfl_xor(mx, m2));
        float e0 = expf(s0 - mx), e1 = expf(s1 - mx);
        float e2 = (lane < 16) ? expf(s2 - mx) : 0.f;
        float sum = e0 + e1 + e2;
        #pragma unroll
        for (int m2 = 1; m2 < 64; m2 <<= 1) sum += __shfl_xor(sum, m2);
        float inv = 1.f / sum;
        __hip_bfloat16* prow = (__hip_bfloat16*)(lds + P_BASE + row * 336);
        prow[lane] = __float2bfloat16(e0 * inv);
        prow[lane + 64] = __float2bfloat16(e1 * inv);
        if (lane < 32) prow[lane + 128] = __float2bfloat16((lane < 16) ? e2 * inv : 0.f);
    }
    __syncthreads();

    // PV: wave owns 16 output dims
    f32x4 acc2[2] = {};
    #pragma unroll
    for (int mt = 0; mt < 2; ++mt)
        #pragma unroll
        for (int ks = 0; ks < 5; ++ks) {
            bf16x8 a  = *(const bf16x8*)(lds + P_BASE + (mt * 16 + fr) * 336 + ks * 64 + kg * 16);
            bf16x8 bb = *(const bf16x8*)(lds + VT_BASE + (wv * 16 + fr) * 336 + ks * 64 + kg * 16);
            acc2[mt] = __builtin_amdgcn_mfma_f32_16x16x32_bf16(a, bb, acc2[mt], 0, 0, 0);
        }
    #pragma unroll
    for (int mt = 0; mt < 2; ++mt)
        #pragma unroll
        for (int r = 0; r < 4; ++r) {
            int t = q0 + mt * 16 + kg * 4 + r;
            if (t <= 128)
                aout[(qrow0 + t) * 512 + hh * 64 + wv * 16 + fr] = __float2bfloat16(acc2[mt][r]);
        }
}

// ---------------- ACT bookkeeping + LN(curr) + blend + h_out ----------------
__global__ __launch_bounds__(256)
void haltblend(const float* __restrict__ curr, const float* __restrict__ s,
               const float* __restrict__ o, float* __restrict__ zbuf,
               float* __restrict__ lanh, float* __restrict__ lah,
               float* __restrict__ h, __hip_bfloat16* __restrict__ hb,
               float* __restrict__ hout, float* __restrict__ stats)
{
    int row = blockIdx.x, tid = threadIdx.x;
    float z0 = zbuf[row * 2 + 0] + 2.f;
    float z1 = zbuf[row * 2 + 1] - 2.f;
    float mxz = fmaxf(z0, z1);
    float lse = mxz + logf(expf(z0 - mxz) + expf(z1 - mxz));
    float lg0 = z0 - lse, lg1 = z1 - lse;
    float ln_ = lanh[row], la_ = lah[row];
    float lhalt = ln_ + lg1;
    float hl = expf(la_);            // PRE-update lah
    float ph = expf(lhalt);

    const float* rp = curr + (size_t)row * 512;
    float x0 = rp[tid], x1 = rp[tid + 256];
    float sum = x0 + x1, sq = x0 * x0 + x1 * x1;
    #pragma unroll
    for (int m2 = 1; m2 < 64; m2 <<= 1) { sum += __shfl_xor(sum, m2); sq += __shfl_xor(sq, m2); }
    __shared__ float ssum[4], ssq[4];
    if ((tid & 63) == 0) { ssum[tid >> 6] = sum; ssq[tid >> 6] = sq; }
    __syncthreads();
    float tot = ssum[0] + ssum[1] + ssum[2] + ssum[3];
    float totq = ssq[0] + ssq[1] + ssq[2] + ssq[3];
    float mean = tot * (1.f / 512.f);
    float inv = rsqrtf(totq * (1.f / 512.f) - mean * mean + EPSLN);

    if (tid == 0) {
        lanh[row] = ln_ + lg0;
        float m3 = fmaxf(la_, lhalt);
        lah[row] = m3 + logf(expf(la_ - m3) + expf(lhalt - m3));
        zbuf[row * 2 + 0] = 0.f;
        zbuf[row * 2 + 1] = 0.f;
        stats[row * 2 + 0] = 0.f;    // reset LN stats for next iteration's Wo epilogue
        stats[row * 2 + 1] = 0.f;
    }

    float cl0 = (x0 - mean) * inv * s[tid] + o[tid];
    float cl1 = (x1 - mean) * inv * s[tid + 256] + o[tid + 256];
    size_t i0 = (size_t)row * 512 + tid;
    float h0n = hl * h[i0] + (1.f - hl) * cl0;
    float h1n = hl * h[i0 + 256] + (1.f - hl) * cl1;
    h[i0] = h0n; h[i0 + 256] = h1n;
    hb[i0] = __float2bfloat16(h0n); hb[i0 + 256] = __float2bfloat16(h1n);
    hout[i0] += ph * cl0;
    hout[i0 + 256] += ph * cl1;
}

// ---------------- setup kernels ----------------
__global__ __launch_bounds__(256)
void emb_kernel(const float* __restrict__ x, const float* __restrict__ We,
                const float* __restrict__ eos, const float* __restrict__ s,
                const float* __restrict__ o, float* __restrict__ h,
                __hip_bfloat16* __restrict__ hb)
{
    int row = blockIdx.x, tid = threadIdx.x;
    int b = row / Sc, t = row % Sc;
    __shared__ float xs[64];
    if (t != 128 && tid < 64) xs[tid] = x[((size_t)b * 128 + t) * 64 + tid];
    __syncthreads();
    float v0, v1;
    if (t == 128) {
        v0 = eos[tid]; v1 = eos[tid + 256];
    } else {
        v0 = 0.f; v1 = 0.f;
        #pragma unroll 8
        for (int k = 0; k < 64; ++k) {
            float xv = xs[k];
            v0 = fmaf(xv, We[k * 512 + tid], v0);
            v1 = fmaf(xv, We[k * 512 + tid + 256], v1);
        }
    }
    float sum = v0 + v1, sq = v0 * v0 + v1 * v1;
    #pragma unroll
    for (int m2 = 1; m2 < 64; m2 <<= 1) { sum += __shfl_xor(sum, m2); sq += __shfl_xor(sq, m2); }
    __shared__ float ssum[4], ssq[4];
    if ((tid & 63) == 0) { ssum[tid >> 6] = sum; ssq[tid >> 6] = sq; }
    __syncthreads();
    float tot = ssum[0] + ssum[1] + ssum[2] + ssum[3];
    float totq = ssq[0] + ssq[1] + ssq[2] + ssq[3];
    float mean = tot * (1.f / 512.f);
    float inv = rsqrtf(totq * (1.f / 512.f) - mean * mean + EPSLN);
    float h0 = (v0 - mean) * inv * s[tid] + o[tid];
    float h1 = (v1 - mean) * inv * s[tid + 256] + o[tid + 256];
    h[(size_t)row * 512 + tid] = h0;
    h[(size_t)row * 512 + tid + 256] = h1;
    hb[(size_t)row * 512 + tid] = __float2bfloat16(h0);
    hb[(size_t)row * 512 + tid + 256] = __float2bfloat16(h1);
}

__global__ __launch_bounds__(256)
void rk7_kernel(const float* __restrict__ pos, const float* __restrict__ Wk,
                const float* __restrict__ bk, float* __restrict__ rk7)
{
    int c = blockIdx.x, tid = threadIdx.x;
    __shared__ float ps[512];
    ps[tid] = pos[c * 512 + tid];
    ps[tid + 256] = pos[c * 512 + tid + 256];
    __syncthreads();
    float a0 = bk[tid], a1 = bk[tid + 256];
    for (int k = 0; k < 512; ++k) {
        float pv = ps[k];
        a0 = fmaf(pv, Wk[(size_t)k * 512 + tid], a0);
        a1 = fmaf(pv, Wk[(size_t)k * 512 + tid + 256], a1);
    }
    rk7[c * 512 + tid] = a0;
    rk7[c * 512 + tid + 256] = a1;
}

__global__ __launch_bounds__(256)
void pack_qkvT(const float* __restrict__ Wq, const float* __restrict__ Wk,
               const float* __restrict__ Wv, __hip_bfloat16* __restrict__ Wt)
{
    int idx = blockIdx.x * 256 + threadIdx.x;
    if (idx >= 1536 * 512) return;
    int n = idx >> 9, k = idx & 511;
    const float* src = (n < 512) ? Wq : (n < 1024) ? Wk : Wv;
    int nc = n & 511;
    Wt[idx] = __float2bfloat16(src[(size_t)k * 512 + nc]);
}

__global__ __launch_bounds__(256)
void transposeT(const float* __restrict__ W, __hip_bfloat16* __restrict__ Wt, int K, int N)
{
    int idx = blockIdx.x * 256 + threadIdx.x;
    if (idx >= K * N) return;
    int n = idx / K, k = idx - n * K;
    Wt[idx] = __float2bfloat16(W[(size_t)k * N + n]);
}

// Wt[n][k] = bf16(W[k][n] * s[k])   (fold LN scale into W1)
__global__ __launch_bounds__(256)
void transposeT_scale(const float* __restrict__ W, const float* __restrict__ s,
                      __hip_bfloat16* __restrict__ Wt, int K, int N)
{
    int idx = blockIdx.x * 256 + threadIdx.x;
    if (idx >= K * N) return;
    int n = idx / K, k = idx - n * K;
    Wt[idx] = __float2bfloat16(W[(size_t)k * N + n] * s[k]);
}

// w1sum[n] = sum_k s[k]*W[k][n];  b1f[n] = b[n] + sum_k o[k]*W[k][n]
__global__ __launch_bounds__(256)
void fold_w1(const float* __restrict__ W, const float* __restrict__ s,
             const float* __restrict__ o, const float* __restrict__ b,
             float* __restrict__ w1sum, float* __restrict__ b1f, int K, int N)
{
    int n = blockIdx.x * 256 + threadIdx.x;
    if (n >= N) return;
    float ws = 0.f, bo_ = b[n];
    for (int k = 0; k < K; ++k) {
        float w = W[(size_t)k * N + n];
        ws = fmaf(s[k], w, ws);
        bo_ = fmaf(o[k], w, bo_);
    }
    w1sum[n] = ws;
    b1f[n] = bo_;
}

__global__ __launch_bounds__(256)
void transposeT_split(const float* __restrict__ W, __hip_bfloat16* __restrict__ Whi,
                      __hip_bfloat16* __restrict__ Wlo, int K, int N)
{
    int idx = blockIdx.x * 256 + threadIdx.x;
    if (idx >= K * N) return;
    int n = idx / K, k = idx - n * K;
    float v = W[(size_t)k * N + n];
    __hip_bfloat16 hi = __float2bfloat16(v);
    Whi[idx] = hi;
    Wlo[idx] = __float2bfloat16(v - __bfloat162float(hi));
}

__global__ __launch_bounds__(256)
void pack_bias(const float* __restrict__ bq, const float* __restrict__ bk,
               const float* __restrict__ bv, float* __restrict__ bqkv)
{
    int idx = blockIdx.x * 256 + threadIdx.x;
    if (idx < 1536)
        bqkv[idx] = (idx < 512) ? bq[idx] : (idx < 1024) ? bk[idx - 512] : bv[idx - 1024];
}

__global__ __launch_bounds__(256)
void init_kernel(float* __restrict__ lanh, float* __restrict__ lah,
                 float* __restrict__ zbuf, float* __restrict__ stats)
{
    int idx = blockIdx.x * 256 + threadIdx.x;
    if (idx < Mc) {
        lanh[idx] = 0.f; lah[idx] = -64.f;
        zbuf[idx * 2 + 0] = 0.f; zbuf[idx * 2 + 1] = 0.f;
    }
    if (idx < MP) {
        stats[idx * 2 + 0] = 0.f; stats[idx * 2 + 1] = 0.f;
    }
}

// ---------------- host launcher ----------------
extern "C" void kernel_launch(void* const* d_in, const int* in_sizes, int n_in,
                              void* d_out, int out_size, void* d_ws, size_t ws_size,
                              hipStream_t stream)
{
    const float* x     = (const float*)d_in[0];
    const float* We    = (const float*)d_in[1];
    const float* eos   = (const float*)d_in[2];
    const float* Wq    = (const float*)d_in[3];
    const float* bq    = (const float*)d_in[4];
    const float* Wk    = (const float*)d_in[5];
    const float* bk    = (const float*)d_in[6];
    const float* Wv    = (const float*)d_in[7];
    const float* bv    = (const float*)d_in[8];
    const float* Wo    = (const float*)d_in[9];
    const float* bo    = (const float*)d_in[10];
    const float* cbias = (const float*)d_in[11];
    const float* rbias = (const float*)d_in[12];
    const float* pos   = (const float*)d_in[13];
    const float* ln2s  = (const float*)d_in[14];
    const float* ln2o  = (const float*)d_in[15];
    const float* lnos  = (const float*)d_in[16];
    const float* lnoo  = (const float*)d_in[17];
    const float* W1    = (const float*)d_in[18];
    const float* b1    = (const float*)d_in[19];
    const float* W2    = (const float*)d_in[20];
    const float* b2    = (const float*)d_in[21];
    const float* Wh1   = (const float*)d_in[22];
    const float* bh1   = (const float*)d_in[23];
    const float* Wh2   = (const float*)d_in[24];
    (void)in_sizes; (void)n_in; (void)ws_size;

    char* wp = (char*)d_ws;
    auto alloc = [&](size_t bytes) { char* p = wp; wp += (bytes + 255) & ~(size_t)255; return p; };
    float*          h     = (float*)alloc((size_t)MP * 512 * 4);
    __hip_bfloat16* hb    = (__hip_bfloat16*)alloc((size_t)MP * 512 * 2);
    __hip_bfloat16* qkvb  = (__hip_bfloat16*)alloc((size_t)MP * 1536 * 2);
    __hip_bfloat16* abufb = (__hip_bfloat16*)alloc((size_t)MP * 512 * 2);
    float*          hmid  = (float*)alloc((size_t)MP * 512 * 4);
    __hip_bfloat16* hmidb = (__hip_bfloat16*)alloc((size_t)MP * 512 * 2);
    __hip_bfloat16* g1b   = (__hip_bfloat16*)alloc((size_t)MP * 1024 * 2);
    float*          curr  = (float*)alloc((size_t)MP * 512 * 4);
    __hip_bfloat16* chi   = (__hip_bfloat16*)alloc((size_t)MP * 512 * 2);
    __hip_bfloat16* clo   = (__hip_bfloat16*)alloc((size_t)MP * 512 * 2);
    __hip_bfloat16* WqkvT = (__hip_bfloat16*)alloc((size_t)1536 * 512 * 2);
    __hip_bfloat16* WoT   = (__hip_bfloat16*)alloc((size_t)512 * 512 * 2);
    __hip_bfloat16* W1T   = (__hip_bfloat16*)alloc((size_t)1024 * 512 * 2);
    __hip_bfloat16* W2T   = (__hip_bfloat16*)alloc((size_t)512 * 1024 * 2);
    __hip_bfloat16* Wh1Th = (__hip_bfloat16*)alloc((size_t)512 * 512 * 2);
    __hip_bfloat16* Wh1Tl = (__hip_bfloat16*)alloc((size_t)512 * 512 * 2);
    float*          bqkv  = (float*)alloc(1536 * 4);
    float*          w1sum = (float*)alloc(1024 * 4);
    float*          b1f   = (float*)alloc(1024 * 4);
    float*          rk7   = (float*)alloc(7 * 512 * 4);
    float*          lanh  = (float*)alloc(Mc * 4);
    float*          lah   = (float*)alloc(Mc * 4);
    float*          zbuf  = (float*)alloc((size_t)Mc * 2 * 4);
    float*          stats = (float*)alloc((size_t)MP * 2 * 4);
    float* hout = (float*)d_out;

    hipMemsetAsync(d_out, 0, (size_t)out_size * sizeof(float), stream);
    init_kernel<<<(MP + 255) / 256, 256, 0, stream>>>(lanh, lah, zbuf, stats);
    pack_qkvT<<<(1536 * 512 + 255) / 256, 256, 0, stream>>>(Wq, Wk, Wv, WqkvT);
    transposeT<<<(512 * 512 + 255) / 256, 256, 0, stream>>>(Wo, WoT, 512, 512);
    transposeT_scale<<<(512 * 1024 + 255) / 256, 256, 0, stream>>>(W1, ln2s, W1T, 512, 1024);
    fold_w1<<<4, 256, 0, stream>>>(W1, ln2s, ln2o, b1, w1sum, b1f, 512, 1024);
    transposeT<<<(1024 * 512 + 255) / 256, 256, 0, stream>>>(W2, W2T, 1024, 512);
    transposeT_split<<<(512 * 512 + 255) / 256, 256, 0, stream>>>(Wh1, Wh1Th, Wh1Tl, 512, 512);
    pack_bias<<<(1536 + 255) / 256, 256, 0, stream>>>(bq, bk, bv, bqkv);
    rk7_kernel<<<7, 256, 0, stream>>>(pos, Wk, bk, rk7);
    emb_kernel<<<Mc, 256, 0, stream>>>(x, We, eos, lnos, lnoo, h, hb);

    for (int it = 0; it < ITERS; ++it) {
        mgemm<3, 64><<<dim3(24, 33), 256, 0, stream>>>(
            hb, WqkvT, bqkv, nullptr, nullptr, qkvb, nullptr, nullptr, nullptr, Mc, 1536, 512);
        attn_mfma<<<dim3(5, 8, 16), 256, 0, stream>>>(qkvb, rk7, cbias, rbias, abufb);
        mgemm<5, 32><<<dim3(8, 66), 256, 0, stream>>>(
            abufb, WoT, bo, h, hmid, hmidb, nullptr, stats, nullptr, Mc, 512, 512);
        mgemm<6, 32><<<dim3(16, 66), 256, 0, stream>>>(
            hmidb, W1T, b1f, nullptr, nullptr, g1b, nullptr, stats, w1sum, Mc, 1024, 512);
        mgemm<4, 32><<<dim3(8, 66), 256, 0, stream>>>(
            g1b, W2T, b2, hmid, curr, chi, clo, nullptr, nullptr, Mc, 512, 1024);
        halt_gemm<<<dim3(8, 66), 256, 0, stream>>>(chi, clo, Wh1Th, Wh1Tl, bh1, Wh2, zbuf, Mc);
        haltblend<<<Mc, 256, 0, stream>>>(curr, lnos, lnoo, zbuf, lanh, lah, h, hb, hout, stats);
    }
}